// Round 6
// baseline (3676.149 us; speedup 1.0000x reference)
//
#include <hip/hip_runtime.h>
#include <hip/hip_bf16.h>
#include <cmath>

static constexpr int BB  = 8;
static constexpr int HW  = 64;
static constexpr int NN  = HW * HW;     // 4096
static constexpr int CC  = 256;
static constexpr int CIN = 64;
static constexpr int DH  = 1024;
static constexpr int MM  = BB * NN;     // 32768

__device__ __forceinline__ float siluf(float x) { return x / (1.f + expf(-x)); }
__device__ __forceinline__ float sigmf(float x) { return 1.f / (1.f + expf(-x)); }
__device__ __forceinline__ float geluf(float x) {
  float t = tanhf(0.7978845608028654f * (x + 0.044715f * x * x * x));
  return 0.5f * x * (1.f + t);
}

// ---------- pos table [N][C] ----------
__global__ __launch_bounds__(256) void pos_kern(float* __restrict__ pos) {
  int n = blockIdx.x, o = threadIdx.x;
  int yy = n >> 6, xx = n & 63;
  int i = o & 63, q = o >> 6;
  float omega = powf(10000.f, -(float)i / 64.f);
  float coord = (q < 2) ? (float)xx : (float)yy;
  float ang = coord * omega;
  pos[(size_t)n * CC + o] = (q & 1) ? cosf(ang) : sinf(ang);
}

// ---------- in_proj + SiLU ----------
__global__ __launch_bounds__(256) void inproj_kern(const float* __restrict__ X,
                                                   const float* __restrict__ W,
                                                   float* __restrict__ H) {
  int gb = blockIdx.x;                 // [0, MM)
  int n = gb & (NN - 1), b = gb >> 12;
  int o = threadIdx.x;
  __shared__ float xs[CIN];
  if (o < CIN) xs[o] = X[((size_t)(b * CIN + o)) * NN + n];
  __syncthreads();
  float acc = 0.f;
#pragma unroll
  for (int k = 0; k < CIN; ++k) acc += xs[k] * W[o * CIN + k];
  H[(size_t)gb * CC + o] = siluf(acc);
}

// ---------- plain GEMM: Y[m,o] = sum_k X[m,k]*W[o,k] (+bias) ----------
template <int KD>
__global__ __launch_bounds__(256) void gemm_kern(const float* __restrict__ X,
                                                 const float* __restrict__ W,
                                                 const float* __restrict__ bias,
                                                 float* __restrict__ Y, int Od) {
  __shared__ float xs[8][KD];
  int m0 = blockIdx.x * 8;
  int o  = blockIdx.y * 256 + threadIdx.x;
  for (int idx = threadIdx.x; idx < 8 * KD; idx += 256) {
    int r = idx / KD, k = idx % KD;
    xs[r][k] = X[(size_t)(m0 + r) * KD + k];
  }
  __syncthreads();
  float acc[8] = {};
  const float* wrow = W + (size_t)o * KD;
  for (int k = 0; k < KD; ++k) {
    float w = wrow[k];
#pragma unroll
    for (int r = 0; r < 8; ++r) acc[r] += xs[r][k] * w;
  }
  float bb = bias ? bias[o] : 0.f;
#pragma unroll
  for (int r = 0; r < 8; ++r) Y[(size_t)(m0 + r) * Od + o] = acc[r] + bb;
}

// ---------- phi = relu(psi * (lin + pos))^2, per-batch [N*C] ----------
__global__ __launch_bounds__(256) void phi_kern(const float* __restrict__ lin,
                                                const float* __restrict__ pos,
                                                const float* __restrict__ psi,
                                                float* __restrict__ phi) {
  size_t i = (size_t)blockIdx.x * 256 + threadIdx.x;
  float v = psi[i] * (lin[i] + pos[i]);
  v = fmaxf(v, 0.f);
  phi[i] = v * v;
}

// ---------- kv partials (per batch): part[ks][c][d] ----------
__global__ __launch_bounds__(256) void kvpart_kern(const float* __restrict__ PK,
                                                   const float* __restrict__ V,
                                                   float* __restrict__ part) {
  int c0 = blockIdx.x * 64, d0 = blockIdx.y * 64, ks = blockIdx.z;
  __shared__ float Ks[16][68];
  __shared__ float Vs[16][68];
  int tid = threadIdx.x, tx = tid & 15, ty = tid >> 4;
  float acc[4][4] = {};
  int n0s = ks * (NN / 8);
  for (int n0 = n0s; n0 < n0s + NN / 8; n0 += 16) {
    int cc = tid & 63, kk0 = tid >> 6;
#pragma unroll
    for (int i = 0; i < 4; ++i) {
      int kk = kk0 * 4 + i;
      size_t base = (size_t)(n0 + kk) * CC;
      Ks[kk][cc] = PK[base + c0 + cc];
      Vs[kk][cc] = V[base + d0 + cc];
    }
    __syncthreads();
#pragma unroll
    for (int kk = 0; kk < 16; ++kk) {
      float kvv[4], vv[4];
#pragma unroll
      for (int a = 0; a < 4; ++a) kvv[a] = Ks[kk][ty * 4 + a];
#pragma unroll
      for (int c = 0; c < 4; ++c) vv[c] = Vs[kk][tx * 4 + c];
#pragma unroll
      for (int a = 0; a < 4; ++a)
#pragma unroll
        for (int c = 0; c < 4; ++c) acc[a][c] += kvv[a] * vv[c];
    }
    __syncthreads();
  }
#pragma unroll
  for (int a = 0; a < 4; ++a)
#pragma unroll
    for (int c = 0; c < 4; ++c)
      part[((size_t)ks * CC + c0 + ty * 4 + a) * CC + d0 + tx * 4 + c] = acc[a][c];
}

// ---------- kvT[d][c] = sum_ks part[ks][c][d] ----------
__global__ __launch_bounds__(256) void kvred_kern(const float* __restrict__ part,
                                                  float* __restrict__ kvT) {
  int c = blockIdx.x, d = threadIdx.x;
  float s = 0.f;
#pragma unroll
  for (int ks = 0; ks < 8; ++ks) s += part[((size_t)ks * CC + c) * CC + d];
  kvT[(size_t)d * CC + c] = s;
}

// ---------- ksum[c] = sum_n phiK[n][c], per batch; LDS tree ----------
__global__ __launch_bounds__(256) void csum_kern(const float* __restrict__ PK,
                                                 float* __restrict__ ksum) {
  int c = blockIdx.x, t = threadIdx.x;
  float s = 0.f;
  for (int k = 0; k < 16; ++k) s += PK[(size_t)(t + 256 * k) * CC + c];
  __shared__ float sa[256];
  sa[t] = s; __syncthreads();
  for (int st = 128; st > 0; st >>= 1) {
    if (t < st) sa[t] += sa[t + st];
    __syncthreads();
  }
  if (t == 0) ksum[c] = sa[0];
}

// ---------- rden[m] = 1/(phiQ[m,:].ksum + eps), per batch; LDS tree ----------
__global__ __launch_bounds__(256) void den_kern(const float* __restrict__ PQ,
                                                const float* __restrict__ ksum,
                                                float* __restrict__ rden) {
  int m = blockIdx.x, c = threadIdx.x;
  __shared__ float sa[256];
  sa[c] = PQ[(size_t)m * CC + c] * ksum[c];
  __syncthreads();
  for (int st = 128; st > 0; st >>= 1) {
    if (c < st) sa[c] += sa[c + st];
    __syncthreads();
  }
  if (c == 0) rden[m] = 1.f / (sa[0] + 1e-5f);
}

// ---------- numb[m][c] *= rden[m] ----------
__global__ __launch_bounds__(256) void div_kern(float* __restrict__ numb,
                                                const float* __restrict__ rden) {
  size_t i = (size_t)blockIdx.x * 256 + threadIdx.x;
  numb[i] *= rden[i >> 8];
}

// ---------- S = X + Y ----------
__global__ __launch_bounds__(256) void add_kern(const float* __restrict__ X,
                                                const float* __restrict__ Y,
                                                float* __restrict__ S) {
  size_t i = (size_t)blockIdx.x * 256 + threadIdx.x;
  S[i] = X[i] + Y[i];
}

// ---------- A += 2*H ----------
__global__ __launch_bounds__(256) void resid_kern(float* __restrict__ A,
                                                  const float* __restrict__ H) {
  size_t i = (size_t)blockIdx.x * 256 + threadIdx.x;
  A[i] += 2.f * H[i];
}

// ---------- DyT with LDS tree reduction ----------
__global__ __launch_bounds__(256) void dyt_kern(const float* __restrict__ X,
                                                const float* __restrict__ g,
                                                const float* __restrict__ bt,
                                                float* __restrict__ T) {
  int m = blockIdx.x, c = threadIdx.x;
  size_t idx = (size_t)m * CC + c;
  float x = X[idx];
  __shared__ float sa[256], qa[256];
  sa[c] = x; qa[c] = x * x;
  __syncthreads();
  for (int st = 128; st > 0; st >>= 1) {
    if (c < st) { sa[c] += sa[c + st]; qa[c] += qa[c + st]; }
    __syncthreads();
  }
  float sum = sa[0], sq = qa[0];
  float mu = sum * (1.f / 256.f);
  float var = (sq - 256.f * mu * mu) * (1.f / 255.f);
  float sd = sqrtf(fmaxf(var, 0.f)) + 1e-5f;
  T[idx] = tanhf(g[c] * (x - mu) / sd + bt[c]);
}

// ---------- pool[b][c] = sum_n T[b,n,c]; LDS tree ----------
__global__ __launch_bounds__(256) void pool_kern(const float* __restrict__ T,
                                                 float* __restrict__ pool) {
  int b = blockIdx.x, c = blockIdx.y, t = threadIdx.x;
  float s = 0.f;
  for (int k = 0; k < 16; ++k)
    s += T[((size_t)b * NN + t + 256 * k) * CC + c];
  __shared__ float sa[256];
  sa[t] = s; __syncthreads();
  for (int st = 128; st > 0; st >>= 1) {
    if (t < st) sa[t] += sa[t + st];
    __syncthreads();
  }
  if (t == 0) pool[b * CC + c] = sa[0];
}

// ---------- gate[b][o] = sigmoid(m_w . pool[b]/4096 + m_b) ----------
__global__ __launch_bounds__(256) void gate_kern(const float* __restrict__ pool,
                                                 const float* __restrict__ w,
                                                 const float* __restrict__ bias,
                                                 float* __restrict__ gate) {
  int b = blockIdx.x, o = threadIdx.x;
  __shared__ float p[CC];
  p[o] = pool[b * CC + o] * (1.f / 4096.f);
  __syncthreads();
  float s = bias[o];
  for (int c = 0; c < CC; ++c) s += p[c] * w[o * CC + c];
  gate[b * CC + o] = sigmf(s);
}

// ---------- O = T * gate[b][c] ----------
__global__ __launch_bounds__(256) void scale_kern(const float* __restrict__ T,
                                                  const float* __restrict__ gate,
                                                  float* __restrict__ O_) {
  size_t i = (size_t)blockIdx.x * 256 + threadIdx.x;
  int b = (int)(i >> 20);
  int c = (int)(i & (CC - 1));
  O_[i] = T[i] * gate[b * CC + c];
}

// ---------- depthwise 3x3 + act, per batch; channel-block grid ----------
template <int CHN, int ACT>  // ACT 0=sigmoid 1=gelu
__global__ __launch_bounds__(256) void dwconv_kern(const float* __restrict__ X,
                                                   const float* __restrict__ w,
                                                   const float* __restrict__ bias,
                                                   float* __restrict__ Y) {
  int c = blockIdx.x * 64 + (threadIdx.x & 63);
  int yy = blockIdx.y;
  int xq = threadIdx.x >> 6;       // 0..3
  float wr[9];
#pragma unroll
  for (int j = 0; j < 9; ++j) wr[j] = w[c * 9 + j];
  float bb = bias[c];
  for (int x0 = xq; x0 < HW; x0 += 4) {
    float acc = bb;
#pragma unroll
    for (int ky = 0; ky < 3; ++ky) {
      int y2 = yy + ky - 1;
      if (y2 < 0 || y2 >= HW) continue;
#pragma unroll
      for (int kx = 0; kx < 3; ++kx) {
        int x2 = x0 + kx - 1;
        if (x2 < 0 || x2 >= HW) continue;
        acc += X[((size_t)y2 * HW + x2) * CHN + c] * wr[ky * 3 + kx];
      }
    }
    Y[((size_t)yy * HW + x0) * CHN + c] = (ACT == 0) ? sigmf(acc) : geluf(acc);
  }
}

// ---------- out_proj + SiLU -> FLOAT32 NCHW ----------
__global__ __launch_bounds__(256) void outproj_kern(const float* __restrict__ Y,
                                                    const float* __restrict__ W,
                                                    float* __restrict__ Out) {
  __shared__ float ys[16][CC];
  int m0 = blockIdx.x * 16, b = blockIdx.y;
  const float* Yb = Y + (size_t)b * NN * CC;
  for (int idx = threadIdx.x; idx < 16 * CC; idx += 256) {
    int r = idx >> 8, k = idx & 255;
    ys[r][k] = Yb[(size_t)(m0 + r) * CC + k];
  }
  __syncthreads();
  int o = threadIdx.x & 63, rg = threadIdx.x >> 6;
  const float* wrow = W + o * CC;
  float acc[4] = {};
  for (int k = 0; k < CC; ++k) {
    float w = wrow[k];
#pragma unroll
    for (int j = 0; j < 4; ++j) acc[j] += ys[rg * 4 + j][k] * w;
  }
#pragma unroll
  for (int j = 0; j < 4; ++j)
    Out[((size_t)(b * CIN + o)) * NN + m0 + rg * 4 + j] = siluf(acc[j]);
}

extern "C" void kernel_launch(void* const* d_in, const int* in_sizes, int n_in,
                              void* d_out, int out_size, void* d_ws, size_t ws_size,
                              hipStream_t stream) {
  (void)in_sizes; (void)n_in; (void)out_size; (void)ws_size;
  const float* x       = (const float*)d_in[0];
  const float* in_proj = (const float*)d_in[1];
  const float* wq_w = (const float*)d_in[2];   const float* wq_b = (const float*)d_in[3];
  const float* wk_w = (const float*)d_in[4];   const float* wk_b = (const float*)d_in[5];
  const float* wv_w = (const float*)d_in[6];   const float* wv_b = (const float*)d_in[7];
  const float* wo_w = (const float*)d_in[8];   const float* wo_b = (const float*)d_in[9];
  const float* psi_w = (const float*)d_in[10]; const float* psi_b = (const float*)d_in[11];
  const float* dyt_g = (const float*)d_in[12]; const float* dyt_b = (const float*)d_in[13];
  const float* m1_w = (const float*)d_in[14];  const float* m1_b = (const float*)d_in[15];
  const float* m2_w = (const float*)d_in[16];  const float* m2_b = (const float*)d_in[17];
  const float* we_w = (const float*)d_in[18];  const float* we_b = (const float*)d_in[19];
  const float* dw_w = (const float*)d_in[20];  const float* dw_b = (const float*)d_in[21];
  const float* wp_w = (const float*)d_in[22];  const float* wp_b = (const float*)d_in[23];
  const float* wout = (const float*)d_in[24];
  float* out = (float*)d_out;     // reference output dtype is float32

  char* ws = (char*)d_ws;
  const size_t MB = 1u << 20;
  const size_t NC = (size_t)NN * CC;
  float* H    = (float*)(ws);               // h -> U1
  float* A    = (float*)(ws + 32 * MB);     // a -> T -> U2 -> Y
  float* scr  = (float*)(ws + 64 * MB);     // S -> e1 -> T2   (32 MiB)
  float* e1   = scr;
  float* e2   = (float*)(ws + 80 * MB);
  float* psiB = (float*)(ws + 96 * MB);
  float* Qlin = (float*)(ws + 100 * MB);
  float* Klin = (float*)(ws + 104 * MB);
  float* Vb   = (float*)(ws + 108 * MB);
  float* phiQ = (float*)(ws + 112 * MB);
  float* phiK = (float*)(ws + 116 * MB);
  float* numb = (float*)(ws + 120 * MB);
  float* pose = (float*)(ws + 124 * MB);
  char*  misc = ws + 128 * MB;
  float* kvpart = (float*)(misc);                   // 2 MiB
  float* kvT    = (float*)(misc + 2 * MB);          // 256 KiB
  float* ksum   = (float*)(misc + 2 * MB + 262144);
  float* rden   = (float*)(misc + 2 * MB + 266240); // 16 KiB
  float* pool1  = (float*)(misc + 2 * MB + 286720);
  float* pool2  = (float*)(misc + 2 * MB + 294912);
  float* gate1  = (float*)(misc + 2 * MB + 303104);
  float* gate2  = (float*)(misc + 2 * MB + 311296);

  dim3 blk(256);
  pos_kern<<<dim3(NN), blk, 0, stream>>>(pose);
  inproj_kern<<<dim3(MM), blk, 0, stream>>>(x, in_proj, H);

  // ---- attention per batch ----
  for (int b = 0; b < BB; ++b) {
    const float* hb = H + (size_t)b * NC;
    float* ab       = A + (size_t)b * NC;
    dwconv_kern<256, 0><<<dim3(4, 64), blk, 0, stream>>>(hb, psi_w, psi_b, psiB);
    gemm_kern<256><<<dim3(512, 1), blk, 0, stream>>>(hb, wq_w, wq_b, Qlin, CC);
    phi_kern<<<dim3(4096), blk, 0, stream>>>(Qlin, pose, psiB, phiQ);
    gemm_kern<256><<<dim3(512, 1), blk, 0, stream>>>(hb, wk_w, wk_b, Klin, CC);
    phi_kern<<<dim3(4096), blk, 0, stream>>>(Klin, pose, psiB, phiK);
    gemm_kern<256><<<dim3(512, 1), blk, 0, stream>>>(hb, wv_w, wv_b, Vb, CC);
    kvpart_kern<<<dim3(4, 4, 8), blk, 0, stream>>>(phiK, Vb, kvpart);
    kvred_kern<<<dim3(CC), blk, 0, stream>>>(kvpart, kvT);
    csum_kern<<<dim3(CC), blk, 0, stream>>>(phiK, ksum);
    den_kern<<<dim3(NN), blk, 0, stream>>>(phiQ, ksum, rden);
    gemm_kern<256><<<dim3(512, 1), blk, 0, stream>>>(phiQ, kvT, nullptr, numb, CC);
    div_kern<<<dim3(4096), blk, 0, stream>>>(numb, rden);
    gemm_kern<256><<<dim3(512, 1), blk, 0, stream>>>(numb, wo_w, wo_b, ab, CC);
  }

  // ---- U1 = mona1(dyt(h + a)) ----
  add_kern<<<dim3(MM), blk, 0, stream>>>(H, A, scr);     // scr = h + a
  dyt_kern<<<dim3(MM), blk, 0, stream>>>(scr, dyt_g, dyt_b, A);   // A = T
  pool_kern<<<dim3(BB, CC), blk, 0, stream>>>(A, pool1);
  gate_kern<<<dim3(BB), blk, 0, stream>>>(pool1, m1_w, m1_b, gate1);
  scale_kern<<<dim3(MM), blk, 0, stream>>>(A, gate1, H); // H = U1

  // ---- EDFFN per batch ----
  for (int b = 0; b < BB; ++b) {
    const float* u1b = H + (size_t)b * NC;
    float* u2b       = A + (size_t)b * NC;
    gemm_kern<256><<<dim3(512, 4), blk, 0, stream>>>(u1b, we_w, we_b, e1, DH);
    dwconv_kern<1024, 1><<<dim3(16, 64), blk, 0, stream>>>(e1, dw_w, dw_b, e2);
    gemm_kern<1024><<<dim3(512, 1), blk, 0, stream>>>(e2, wp_w, wp_b, u2b, CC);
  }
  resid_kern<<<dim3(MM), blk, 0, stream>>>(A, H);        // A = U2 = wp(..) + 2*U1

  // ---- Y = mona2(dyt(U2)) ----
  dyt_kern<<<dim3(MM), blk, 0, stream>>>(A, dyt_g, dyt_b, scr);   // scr = T2
  pool_kern<<<dim3(BB, CC), blk, 0, stream>>>(scr, pool2);
  gate_kern<<<dim3(BB), blk, 0, stream>>>(pool2, m2_w, m2_b, gate2);
  scale_kern<<<dim3(MM), blk, 0, stream>>>(scr, gate2, A);        // A = Y

  outproj_kern<<<dim3(NN / 16, BB), blk, 0, stream>>>(A, wout, out);
}

// Round 7
// 1584.287 us; speedup vs baseline: 2.3204x; 2.3204x over previous
//
#include <hip/hip_runtime.h>
#include <hip/hip_bf16.h>
#include <cmath>

static constexpr int BB  = 8;
static constexpr int HW  = 64;
static constexpr int NN  = HW * HW;     // 4096
static constexpr int CC  = 256;
static constexpr int CIN = 64;
static constexpr int DH  = 1024;
static constexpr int MM  = BB * NN;     // 32768

__device__ __forceinline__ float siluf(float x) { return x / (1.f + expf(-x)); }
__device__ __forceinline__ float sigmf(float x) { return 1.f / (1.f + expf(-x)); }
__device__ __forceinline__ float geluf(float x) {
  float t = tanhf(0.7978845608028654f * (x + 0.044715f * x * x * x));
  return 0.5f * x * (1.f + t);
}

// ---------- pos table [N][C] ----------
__global__ __launch_bounds__(256) void pos_kern(float* __restrict__ pos) {
  int n = blockIdx.x, o = threadIdx.x;
  int yy = n >> 6, xx = n & 63;
  int i = o & 63, q = o >> 6;
  float omega = powf(10000.f, -(float)i / 64.f);
  float coord = (q < 2) ? (float)xx : (float)yy;
  float ang = coord * omega;
  pos[(size_t)n * CC + o] = (q & 1) ? cosf(ang) : sinf(ang);
}

// ---------- in_proj: NCHW(64ch) -> [B*N,256], tiled, + SiLU ----------
__global__ __launch_bounds__(256) void inproj_tile(const float* __restrict__ X,
                                                   const float* __restrict__ W,
                                                   float* __restrict__ H) {
  __shared__ float Xs[16][68];
  __shared__ float Ws[16][68];
  int m0 = blockIdx.x * 64, o0 = blockIdx.y * 64, b = blockIdx.z;
  int tid = threadIdx.x, tx = tid & 15, ty = tid >> 4;
  float acc[4][4] = {};
  for (int k0 = 0; k0 < CIN; k0 += 16) {
    {
      int mm = tid & 63, kk0 = tid >> 6;
#pragma unroll
      for (int i = 0; i < 4; ++i) {
        int kk = kk0 * 4 + i;
        Xs[kk][mm] = X[((size_t)(b * CIN + k0 + kk)) * NN + m0 + mm];
      }
    }
    {
      int kk = tid & 15, oo0 = tid >> 4;
#pragma unroll
      for (int i = 0; i < 4; ++i) {
        int oo = oo0 + i * 16;
        Ws[kk][oo] = W[(size_t)(o0 + oo) * CIN + k0 + kk];
      }
    }
    __syncthreads();
#pragma unroll
    for (int kk = 0; kk < 16; ++kk) {
      float xv[4], wv[4];
#pragma unroll
      for (int a = 0; a < 4; ++a) xv[a] = Xs[kk][ty * 4 + a];
#pragma unroll
      for (int c = 0; c < 4; ++c) wv[c] = Ws[kk][tx * 4 + c];
#pragma unroll
      for (int a = 0; a < 4; ++a)
#pragma unroll
        for (int c = 0; c < 4; ++c) acc[a][c] += xv[a] * wv[c];
    }
    __syncthreads();
  }
#pragma unroll
  for (int a = 0; a < 4; ++a) {
    int m = m0 + ty * 4 + a;
#pragma unroll
    for (int c = 0; c < 4; ++c) {
      int o = o0 + tx * 4 + c;
      H[((size_t)b * NN + m) * CC + o] = siluf(acc[a][c]);
    }
  }
}

// ---------- batched tiled GEMM with fused epilogues ----------
// Y[m,o] = epi( sum_k X[m,k] * W[o,k] ),  m = b*NN + n
enum { EPI_BIAS = 0, EPI_QK = 1, EPI_NUM = 2, EPI_RESID = 3, EPI_OUT = 4 };

template <int EPI, bool WPB>
__global__ __launch_bounds__(256) void gemm_tile(const float* __restrict__ X,
                                                 const float* __restrict__ W,
                                                 const float* __restrict__ bias,
                                                 float* __restrict__ Y, int Kd, int Od,
                                                 const float* __restrict__ aux,
                                                 const float* __restrict__ pose) {
  __shared__ float Xs[16][68];
  __shared__ float Ws[16][68];
  int n0 = blockIdx.x * 64, o0 = blockIdx.y * 64, b = blockIdx.z;
  size_t mbase = (size_t)b * NN;
  const float* Wp = WPB ? (W + (size_t)b * Kd * Od) : W;
  int tid = threadIdx.x, tx = tid & 15, ty = tid >> 4;
  float acc[4][4] = {};
  for (int k0 = 0; k0 < Kd; k0 += 16) {
    int kk = tid & 15, rr0 = tid >> 4;
#pragma unroll
    for (int i = 0; i < 4; ++i) {
      int rr = rr0 + i * 16;
      Xs[kk][rr] = X[(mbase + n0 + rr) * Kd + k0 + kk];
      Ws[kk][rr] = Wp[(size_t)(o0 + rr) * Kd + k0 + kk];
    }
    __syncthreads();
#pragma unroll
    for (int kk2 = 0; kk2 < 16; ++kk2) {
      float xv[4], wv[4];
#pragma unroll
      for (int a = 0; a < 4; ++a) xv[a] = Xs[kk2][ty * 4 + a];
#pragma unroll
      for (int c = 0; c < 4; ++c) wv[c] = Ws[kk2][tx * 4 + c];
#pragma unroll
      for (int a = 0; a < 4; ++a)
#pragma unroll
        for (int c = 0; c < 4; ++c) acc[a][c] += xv[a] * wv[c];
    }
    __syncthreads();
  }
#pragma unroll
  for (int a = 0; a < 4; ++a) {
    int n = n0 + ty * 4 + a;
    size_t m = mbase + n;
#pragma unroll
    for (int c = 0; c < 4; ++c) {
      int o = o0 + tx * 4 + c;
      float v = acc[a][c];
      if constexpr (EPI == EPI_BIAS) {
        v += bias[o];
        Y[m * Od + o] = v;
      } else if constexpr (EPI == EPI_QK) {
        v = (v + bias[o] + pose[(size_t)n * CC + o]) * aux[m * CC + o];
        v = fmaxf(v, 0.f);
        Y[m * Od + o] = v * v;
      } else if constexpr (EPI == EPI_NUM) {
        Y[m * Od + o] = v * aux[m];
      } else if constexpr (EPI == EPI_RESID) {
        Y[m * Od + o] = v + bias[o] + 2.f * aux[m * CC + o];
      } else {  // EPI_OUT: transposed NCHW write + SiLU (no bias)
        Y[(size_t)(b * CIN + o) * NN + n] = siluf(v);
      }
    }
  }
}

// ---------- kv partials batched: part[b*8+ks][c][d] ----------
__global__ __launch_bounds__(256) void kvpart_kern(const float* __restrict__ PK,
                                                   const float* __restrict__ V,
                                                   float* __restrict__ part) {
  int c0 = blockIdx.x * 64, d0 = blockIdx.y * 64;
  int b = blockIdx.z >> 3, ks = blockIdx.z & 7;
  const float* PKb = PK + (size_t)b * NN * CC;
  const float* Vb  = V  + (size_t)b * NN * CC;
  __shared__ float Ks[16][68];
  __shared__ float Vs[16][68];
  int tid = threadIdx.x, tx = tid & 15, ty = tid >> 4;
  float acc[4][4] = {};
  int n0s = ks * (NN / 8);
  for (int n0 = n0s; n0 < n0s + NN / 8; n0 += 16) {
    int cc = tid & 63, kk0 = tid >> 6;
#pragma unroll
    for (int i = 0; i < 4; ++i) {
      int kk = kk0 * 4 + i;
      size_t base = (size_t)(n0 + kk) * CC;
      Ks[kk][cc] = PKb[base + c0 + cc];
      Vs[kk][cc] = Vb[base + d0 + cc];
    }
    __syncthreads();
#pragma unroll
    for (int kk = 0; kk < 16; ++kk) {
      float kvv[4], vv[4];
#pragma unroll
      for (int a = 0; a < 4; ++a) kvv[a] = Ks[kk][ty * 4 + a];
#pragma unroll
      for (int c = 0; c < 4; ++c) vv[c] = Vs[kk][tx * 4 + c];
#pragma unroll
      for (int a = 0; a < 4; ++a)
#pragma unroll
        for (int c = 0; c < 4; ++c) acc[a][c] += kvv[a] * vv[c];
    }
    __syncthreads();
  }
#pragma unroll
  for (int a = 0; a < 4; ++a)
#pragma unroll
    for (int c = 0; c < 4; ++c)
      part[((size_t)blockIdx.z * CC + c0 + ty * 4 + a) * CC + d0 + tx * 4 + c] = acc[a][c];
}

// ---------- kvT[b][d][c] = sum_ks part[b*8+ks][c][d] ----------
__global__ __launch_bounds__(256) void kvred_kern(const float* __restrict__ part,
                                                  float* __restrict__ kvT) {
  int c = blockIdx.x, b = blockIdx.y, d = threadIdx.x;
  float s = 0.f;
#pragma unroll
  for (int ks = 0; ks < 8; ++ks)
    s += part[((size_t)(b * 8 + ks) * CC + c) * CC + d];
  kvT[((size_t)b * CC + d) * CC + c] = s;
}

// ---------- ksum[b][c] = sum_n phiK[b,n,c] ----------
__global__ __launch_bounds__(256) void csum_kern(const float* __restrict__ PK,
                                                 float* __restrict__ ksum) {
  int c = blockIdx.x, b = blockIdx.y, t = threadIdx.x;
  const float* PKb = PK + (size_t)b * NN * CC;
  float s = 0.f;
  for (int k = 0; k < 16; ++k) s += PKb[(size_t)(t + 256 * k) * CC + c];
  __shared__ float sa[256];
  sa[t] = s; __syncthreads();
  for (int st = 128; st > 0; st >>= 1) {
    if (t < st) sa[t] += sa[t + st];
    __syncthreads();
  }
  if (t == 0) ksum[b * CC + c] = sa[0];
}

// ---------- rden[b*NN+n] = 1/(phiQ[n,:].ksum[b,:] + eps) ----------
__global__ __launch_bounds__(256) void den_kern(const float* __restrict__ PQ,
                                                const float* __restrict__ ksum,
                                                float* __restrict__ rden) {
  int n = blockIdx.x, b = blockIdx.y, c = threadIdx.x;
  size_t m = (size_t)b * NN + n;
  __shared__ float sa[256];
  sa[c] = PQ[m * CC + c] * ksum[b * CC + c];
  __syncthreads();
  for (int st = 128; st > 0; st >>= 1) {
    if (c < st) sa[c] += sa[c + st];
    __syncthreads();
  }
  if (c == 0) rden[m] = 1.f / (sa[0] + 1e-5f);
}

// ---------- DyT (optional fused residual add) ----------
template <bool RESID>
__global__ __launch_bounds__(256) void dyt_kern(const float* __restrict__ X,
                                                const float* __restrict__ R,
                                                const float* __restrict__ g,
                                                const float* __restrict__ bt,
                                                float* __restrict__ T) {
  int m = blockIdx.x, c = threadIdx.x;
  size_t idx = (size_t)m * CC + c;
  float x = X[idx];
  if constexpr (RESID) x += R[idx];
  __shared__ float sa[256], qa[256];
  sa[c] = x; qa[c] = x * x;
  __syncthreads();
  for (int st = 128; st > 0; st >>= 1) {
    if (c < st) { sa[c] += sa[c + st]; qa[c] += qa[c + st]; }
    __syncthreads();
  }
  float sum = sa[0], sq = qa[0];
  float mu = sum * (1.f / 256.f);
  float var = (sq - 256.f * mu * mu) * (1.f / 255.f);
  float sd = sqrtf(fmaxf(var, 0.f)) + 1e-5f;
  T[idx] = tanhf(g[c] * (x - mu) / sd + bt[c]);
}

// ---------- pool[b][c] = sum_n T[b,n,c] ----------
__global__ __launch_bounds__(256) void pool_kern(const float* __restrict__ T,
                                                 float* __restrict__ pool) {
  int b = blockIdx.x, c = blockIdx.y, t = threadIdx.x;
  float s = 0.f;
  for (int k = 0; k < 16; ++k)
    s += T[((size_t)b * NN + t + 256 * k) * CC + c];
  __shared__ float sa[256];
  sa[t] = s; __syncthreads();
  for (int st = 128; st > 0; st >>= 1) {
    if (t < st) sa[t] += sa[t + st];
    __syncthreads();
  }
  if (t == 0) pool[b * CC + c] = sa[0];
}

// ---------- gate[b][o] = sigmoid(m_w . pool[b]/4096 + m_b) ----------
__global__ __launch_bounds__(256) void gate_kern(const float* __restrict__ pool,
                                                 const float* __restrict__ w,
                                                 const float* __restrict__ bias,
                                                 float* __restrict__ gate) {
  int b = blockIdx.x, o = threadIdx.x;
  __shared__ float p[CC];
  p[o] = pool[b * CC + o] * (1.f / 4096.f);
  __syncthreads();
  float s = bias[o];
  for (int c = 0; c < CC; ++c) s += p[c] * w[o * CC + c];
  gate[b * CC + o] = sigmf(s);
}

// ---------- O = T * gate[b][c] ----------
__global__ __launch_bounds__(256) void scale_kern(const float* __restrict__ T,
                                                  const float* __restrict__ gate,
                                                  float* __restrict__ O_) {
  size_t i = (size_t)blockIdx.x * 256 + threadIdx.x;
  int b = (int)(i >> 20);
  int c = (int)(i & (CC - 1));
  O_[i] = T[i] * gate[b * CC + c];
}

// ---------- depthwise 3x3 + act, batched ----------
template <int CHN, int ACT>  // ACT 0=sigmoid 1=gelu
__global__ __launch_bounds__(256) void dwconv_kern(const float* __restrict__ X,
                                                   const float* __restrict__ w,
                                                   const float* __restrict__ bias,
                                                   float* __restrict__ Y) {
  int b = blockIdx.z;
  const float* Xb = X + (size_t)b * NN * CHN;
  float* Yb       = Y + (size_t)b * NN * CHN;
  int c = blockIdx.x * 64 + (threadIdx.x & 63);
  int yy = blockIdx.y;
  int xq = threadIdx.x >> 6;
  float wr[9];
#pragma unroll
  for (int j = 0; j < 9; ++j) wr[j] = w[c * 9 + j];
  float bb = bias[c];
  for (int x0 = xq; x0 < HW; x0 += 4) {
    float acc = bb;
#pragma unroll
    for (int ky = 0; ky < 3; ++ky) {
      int y2 = yy + ky - 1;
      if (y2 < 0 || y2 >= HW) continue;
#pragma unroll
      for (int kx = 0; kx < 3; ++kx) {
        int x2 = x0 + kx - 1;
        if (x2 < 0 || x2 >= HW) continue;
        acc += Xb[((size_t)y2 * HW + x2) * CHN + c] * wr[ky * 3 + kx];
      }
    }
    Yb[((size_t)yy * HW + x0) * CHN + c] = (ACT == 0) ? sigmf(acc) : geluf(acc);
  }
}

extern "C" void kernel_launch(void* const* d_in, const int* in_sizes, int n_in,
                              void* d_out, int out_size, void* d_ws, size_t ws_size,
                              hipStream_t stream) {
  (void)in_sizes; (void)n_in; (void)out_size; (void)ws_size;
  const float* x       = (const float*)d_in[0];
  const float* in_proj = (const float*)d_in[1];
  const float* wq_w = (const float*)d_in[2];   const float* wq_b = (const float*)d_in[3];
  const float* wk_w = (const float*)d_in[4];   const float* wk_b = (const float*)d_in[5];
  const float* wv_w = (const float*)d_in[6];   const float* wv_b = (const float*)d_in[7];
  const float* wo_w = (const float*)d_in[8];   const float* wo_b = (const float*)d_in[9];
  const float* psi_w = (const float*)d_in[10]; const float* psi_b = (const float*)d_in[11];
  const float* dyt_g = (const float*)d_in[12]; const float* dyt_b = (const float*)d_in[13];
  const float* m1_w = (const float*)d_in[14];  const float* m1_b = (const float*)d_in[15];
  const float* m2_w = (const float*)d_in[16];  const float* m2_b = (const float*)d_in[17];
  const float* we_w = (const float*)d_in[18];  const float* we_b = (const float*)d_in[19];
  const float* dw_w = (const float*)d_in[20];  const float* dw_b = (const float*)d_in[21];
  const float* wp_w = (const float*)d_in[22];  const float* wp_b = (const float*)d_in[23];
  const float* wout = (const float*)d_in[24];
  float* out = (float*)d_out;

  char* ws = (char*)d_ws;
  const size_t MB = 1u << 20;
  float* H    = (float*)(ws);               // h -> U1
  float* A    = (float*)(ws + 32 * MB);     // a -> U2 -> Y
  float* psiB = (float*)(ws + 64 * MB);     // psi -> num ; later e1 (2-batch)
  float* phiQ = (float*)(ws + 96 * MB);     // later e2
  float* phiK = (float*)(ws + 128 * MB);    // later T (dyt out)
  float* Vb   = (float*)(ws + 160 * MB);
  float* numb = psiB;
  float* e1   = psiB;
  float* e2   = phiQ;
  float* T    = phiK;
  float* kvpart = (float*)(ws + 192 * MB);  // 16 MiB [64][C][C]
  float* kvT    = (float*)(ws + 208 * MB);  // 2 MiB [B][C][C]
  float* pose   = (float*)(ws + 210 * MB);  // 4 MiB
  char*  small  = ws + 214 * MB;
  float* ksum  = (float*)(small);
  float* rden  = (float*)(small + 64 * 1024);    // 128 KiB
  float* pool1 = (float*)(small + 256 * 1024);
  float* pool2 = (float*)(small + 272 * 1024);
  float* gate1 = (float*)(small + 288 * 1024);
  float* gate2 = (float*)(small + 304 * 1024);

  dim3 blk(256);
  const size_t NC = (size_t)NN * CC;

  pos_kern<<<dim3(NN), blk, 0, stream>>>(pose);
  inproj_tile<<<dim3(64, 4, BB), blk, 0, stream>>>(x, in_proj, H);

  // ---- attention (batched) ----
  dwconv_kern<256, 0><<<dim3(4, 64, BB), blk, 0, stream>>>(H, psi_w, psi_b, psiB);
  gemm_tile<EPI_QK, false><<<dim3(64, 4, BB), blk, 0, stream>>>(H, wq_w, wq_b, phiQ, CC, CC, psiB, pose);
  gemm_tile<EPI_QK, false><<<dim3(64, 4, BB), blk, 0, stream>>>(H, wk_w, wk_b, phiK, CC, CC, psiB, pose);
  gemm_tile<EPI_BIAS, false><<<dim3(64, 4, BB), blk, 0, stream>>>(H, wv_w, wv_b, Vb, CC, CC, nullptr, nullptr);
  kvpart_kern<<<dim3(4, 4, 64), blk, 0, stream>>>(phiK, Vb, kvpart);
  kvred_kern<<<dim3(CC, BB), blk, 0, stream>>>(kvpart, kvT);
  csum_kern<<<dim3(CC, BB), blk, 0, stream>>>(phiK, ksum);
  den_kern<<<dim3(NN, BB), blk, 0, stream>>>(phiQ, ksum, rden);
  gemm_tile<EPI_NUM, true><<<dim3(64, 4, BB), blk, 0, stream>>>(phiQ, kvT, nullptr, numb, CC, CC, rden, nullptr);
  gemm_tile<EPI_BIAS, false><<<dim3(64, 4, BB), blk, 0, stream>>>(numb, wo_w, wo_b, A, CC, CC, nullptr, nullptr);

  // ---- U1 = mona1(dyt(h + a)) ----
  dyt_kern<true><<<dim3(MM), blk, 0, stream>>>(H, A, dyt_g, dyt_b, T);
  pool_kern<<<dim3(BB, CC), blk, 0, stream>>>(T, pool1);
  gate_kern<<<dim3(BB), blk, 0, stream>>>(pool1, m1_w, m1_b, gate1);
  scale_kern<<<dim3(MM), blk, 0, stream>>>(T, gate1, H);   // H = U1

  // ---- EDFFN, 2 batches per iteration ----
  for (int p = 0; p < 4; ++p) {
    const float* u1p = H + (size_t)(2 * p) * NC;
    float* u2p       = A + (size_t)(2 * p) * NC;
    gemm_tile<EPI_BIAS, false><<<dim3(64, 16, 2), blk, 0, stream>>>(u1p, we_w, we_b, e1, CC, DH, nullptr, nullptr);
    dwconv_kern<1024, 1><<<dim3(16, 64, 2), blk, 0, stream>>>(e1, dw_w, dw_b, e2);
    gemm_tile<EPI_RESID, false><<<dim3(64, 4, 2), blk, 0, stream>>>(e2, wp_w, wp_b, u2p, DH, CC, u1p, nullptr);
  }

  // ---- Y = mona2(dyt(U2)) ----
  dyt_kern<false><<<dim3(MM), blk, 0, stream>>>(A, nullptr, dyt_g, dyt_b, T);
  pool_kern<<<dim3(BB, CC), blk, 0, stream>>>(T, pool2);
  gate_kern<<<dim3(BB), blk, 0, stream>>>(pool2, m2_w, m2_b, gate2);
  scale_kern<<<dim3(MM), blk, 0, stream>>>(T, gate2, A);   // A = Y

  // ---- out_proj + SiLU, transposed write ----
  gemm_tile<EPI_OUT, false><<<dim3(64, 1, BB), blk, 0, stream>>>(A, wout, nullptr, out, CC, CIN, nullptr, nullptr);
}

// Round 9
// 1233.988 us; speedup vs baseline: 2.9791x; 1.2839x over previous
//
#include <hip/hip_runtime.h>
#include <hip/hip_bf16.h>
#include <cmath>

using bf16 = __hip_bfloat16;
using bf16x8 = __attribute__((ext_vector_type(8))) short;
using f32x4v = __attribute__((ext_vector_type(4))) float;

static constexpr int BB  = 8;
static constexpr int HW  = 64;
static constexpr int NN  = HW * HW;     // 4096
static constexpr int CC  = 256;
static constexpr int CIN = 64;
static constexpr int DH  = 1024;
static constexpr int MM  = BB * NN;     // 32768

__device__ __forceinline__ float siluf(float x) { return x / (1.f + expf(-x)); }
__device__ __forceinline__ float sigmf(float x) { return 1.f / (1.f + expf(-x)); }
__device__ __forceinline__ float geluf(float x) {
  float t = tanhf(0.7978845608028654f * (x + 0.044715f * x * x * x));
  return 0.5f * x * (1.f + t);
}

// ---------- pos table [N][C] ----------
__global__ __launch_bounds__(256) void pos_kern(float* __restrict__ pos) {
  int n = blockIdx.x, o = threadIdx.x;
  int yy = n >> 6, xx = n & 63;
  int i = o & 63, q = o >> 6;
  float omega = powf(10000.f, -(float)i / 64.f);
  float coord = (q < 2) ? (float)xx : (float)yy;
  float ang = coord * omega;
  pos[(size_t)n * CC + o] = (q & 1) ? cosf(ang) : sinf(ang);
}

// ---------- in_proj: NCHW(64ch) -> [B*N,256], tiled, + SiLU ----------
__global__ __launch_bounds__(256) void inproj_tile(const float* __restrict__ X,
                                                   const float* __restrict__ W,
                                                   float* __restrict__ H) {
  __shared__ float Xs[16][68];
  __shared__ float Ws[16][68];
  int m0 = blockIdx.x * 64, o0 = blockIdx.y * 64, b = blockIdx.z;
  int tid = threadIdx.x, tx = tid & 15, ty = tid >> 4;
  float acc[4][4] = {};
  for (int k0 = 0; k0 < CIN; k0 += 16) {
    {
      int mm = tid & 63, kk0 = tid >> 6;
#pragma unroll
      for (int i = 0; i < 4; ++i) {
        int kk = kk0 * 4 + i;
        Xs[kk][mm] = X[((size_t)(b * CIN + k0 + kk)) * NN + m0 + mm];
      }
    }
    {
      int kk = tid & 15, oo0 = tid >> 4;
#pragma unroll
      for (int i = 0; i < 4; ++i) {
        int oo = oo0 + i * 16;
        Ws[kk][oo] = W[(size_t)(o0 + oo) * CIN + k0 + kk];
      }
    }
    __syncthreads();
#pragma unroll
    for (int kk = 0; kk < 16; ++kk) {
      float xv[4], wv[4];
#pragma unroll
      for (int a = 0; a < 4; ++a) xv[a] = Xs[kk][ty * 4 + a];
#pragma unroll
      for (int c = 0; c < 4; ++c) wv[c] = Ws[kk][tx * 4 + c];
#pragma unroll
      for (int a = 0; a < 4; ++a)
#pragma unroll
        for (int c = 0; c < 4; ++c) acc[a][c] += xv[a] * wv[c];
    }
    __syncthreads();
  }
#pragma unroll
  for (int a = 0; a < 4; ++a) {
    int m = m0 + ty * 4 + a;
#pragma unroll
    for (int c = 0; c < 4; ++c) {
      int o = o0 + tx * 4 + c;
      H[((size_t)b * NN + m) * CC + o] = siluf(acc[a][c]);
    }
  }
}

// ---------- batched tiled f32 GEMM with fused epilogues (R7, unchanged) ----------
enum { EPI_BIAS = 0, EPI_QK = 1, EPI_NUM = 2, EPI_RESID = 3, EPI_OUT = 4 };

template <int EPI, bool WPB>
__global__ __launch_bounds__(256) void gemm_tile(const float* __restrict__ X,
                                                 const float* __restrict__ W,
                                                 const float* __restrict__ bias,
                                                 float* __restrict__ Y, int Kd, int Od,
                                                 const float* __restrict__ aux,
                                                 const float* __restrict__ pose) {
  __shared__ float Xs[16][68];
  __shared__ float Ws[16][68];
  int n0 = blockIdx.x * 64, o0 = blockIdx.y * 64, b = blockIdx.z;
  size_t mbase = (size_t)b * NN;
  const float* Wp = WPB ? (W + (size_t)b * Kd * Od) : W;
  int tid = threadIdx.x, tx = tid & 15, ty = tid >> 4;
  float acc[4][4] = {};
  for (int k0 = 0; k0 < Kd; k0 += 16) {
    int kk = tid & 15, rr0 = tid >> 4;
#pragma unroll
    for (int i = 0; i < 4; ++i) {
      int rr = rr0 + i * 16;
      Xs[kk][rr] = X[(mbase + n0 + rr) * Kd + k0 + kk];
      Ws[kk][rr] = Wp[(size_t)(o0 + rr) * Kd + k0 + kk];
    }
    __syncthreads();
#pragma unroll
    for (int kk2 = 0; kk2 < 16; ++kk2) {
      float xv[4], wv[4];
#pragma unroll
      for (int a = 0; a < 4; ++a) xv[a] = Xs[kk2][ty * 4 + a];
#pragma unroll
      for (int c = 0; c < 4; ++c) wv[c] = Ws[kk2][tx * 4 + c];
#pragma unroll
      for (int a = 0; a < 4; ++a)
#pragma unroll
        for (int c = 0; c < 4; ++c) acc[a][c] += xv[a] * wv[c];
    }
    __syncthreads();
  }
#pragma unroll
  for (int a = 0; a < 4; ++a) {
    int n = n0 + ty * 4 + a;
    size_t m = mbase + n;
#pragma unroll
    for (int c = 0; c < 4; ++c) {
      int o = o0 + tx * 4 + c;
      float v = acc[a][c];
      if constexpr (EPI == EPI_BIAS) {
        v += bias[o];
        Y[m * Od + o] = v;
      } else if constexpr (EPI == EPI_QK) {
        v = (v + bias[o] + pose[(size_t)n * CC + o]) * aux[m * CC + o];
        v = fmaxf(v, 0.f);
        Y[m * Od + o] = v * v;
      } else if constexpr (EPI == EPI_NUM) {
        Y[m * Od + o] = v * aux[m];
      } else if constexpr (EPI == EPI_RESID) {
        Y[m * Od + o] = v + bias[o] + 2.f * aux[m * CC + o];
      } else {  // EPI_OUT
        Y[(size_t)(b * CIN + o) * NN + n] = siluf(v);
      }
    }
  }
}

// ---------- NEW: bf16-MFMA GEMM core, f32 in/out (cast during staging) ----------
// Y[m,o] = sum_k X[m,k] * W[o,k] + bias[o]  (+ 2*aux[m,Od,o] if RESID)
__device__ __forceinline__ bf16x8 pack8(const float* s) {
  union { bf16x8 v; bf16 e[8]; } u;
#pragma unroll
  for (int i = 0; i < 8; ++i) u.e[i] = __float2bfloat16(s[i]);
  return u.v;
}

template <int RESID>
__global__ __launch_bounds__(256) void gemm_mfma(const float* __restrict__ X,
                                                 const float* __restrict__ W,
                                                 const float* __restrict__ bias,
                                                 float* __restrict__ Y, int Kd, int Od,
                                                 const float* __restrict__ aux) {
  __shared__ bf16 As[128 * 32];
  __shared__ bf16 Bs[128 * 32];
  int m0 = blockIdx.x * 128, o0 = blockIdx.y * 128;
  int t = threadIdx.x;
  int l = t & 63, w = t >> 6;
  int wm = (w >> 1) * 64, wn = (w & 1) * 64;
  int lr = l & 15, lq = l >> 4;
  f32x4v acc[4][4] = {};
  for (int k0 = 0; k0 < Kd; k0 += 32) {
#pragma unroll
    for (int j = 0; j < 2; ++j) {
      int chunk = j * 256 + t;       // 0..511
      int row = chunk >> 2;          // 0..127
      int kc = (chunk & 3) * 8;
      float xs[8], wsv[8];
      const float* xp = X + (size_t)(m0 + row) * Kd + k0 + kc;
      const float* wp = W + (size_t)(o0 + row) * Kd + k0 + kc;
#pragma unroll
      for (int i = 0; i < 8; ++i) { xs[i] = xp[i]; wsv[i] = wp[i]; }
      *(bf16x8*)(As + row * 32 + kc) = pack8(xs);
      *(bf16x8*)(Bs + row * 32 + kc) = pack8(wsv);
    }
    __syncthreads();
    bf16x8 af[4], bfr[4];
#pragma unroll
    for (int mt = 0; mt < 4; ++mt)
      af[mt] = *(const bf16x8*)(As + (wm + mt * 16 + lr) * 32 + lq * 8);
#pragma unroll
    for (int nt = 0; nt < 4; ++nt)
      bfr[nt] = *(const bf16x8*)(Bs + (wn + nt * 16 + lr) * 32 + lq * 8);
#pragma unroll
    for (int mt = 0; mt < 4; ++mt)
#pragma unroll
      for (int nt = 0; nt < 4; ++nt)
        acc[mt][nt] = __builtin_amdgcn_mfma_f32_16x16x32_bf16(af[mt], bfr[nt], acc[mt][nt], 0, 0, 0);
    __syncthreads();
  }
  // C/D: col = lane&15 (o), row = (lane>>4)*4 + reg (m)
#pragma unroll
  for (int nt = 0; nt < 4; ++nt) {
    int o = o0 + wn + nt * 16 + lr;
    float bv = bias[o];
#pragma unroll
    for (int mt = 0; mt < 4; ++mt) {
      int mb = m0 + wm + mt * 16 + lq * 4;
#pragma unroll
      for (int r = 0; r < 4; ++r) {
        int m = mb + r;
        float v = acc[mt][nt][r] + bv;
        if constexpr (RESID) v += 2.f * aux[(size_t)m * Od + o];
        Y[(size_t)m * Od + o] = v;
      }
    }
  }
}

// ---------- kv partials batched: part[b*8+ks][c][d] ----------
__global__ __launch_bounds__(256) void kvpart_kern(const float* __restrict__ PK,
                                                   const float* __restrict__ V,
                                                   float* __restrict__ part) {
  int c0 = blockIdx.x * 64, d0 = blockIdx.y * 64;
  int b = blockIdx.z >> 3, ks = blockIdx.z & 7;
  const float* PKb = PK + (size_t)b * NN * CC;
  const float* Vb  = V  + (size_t)b * NN * CC;
  __shared__ float Ks[16][68];
  __shared__ float Vs[16][68];
  int tid = threadIdx.x, tx = tid & 15, ty = tid >> 4;
  float acc[4][4] = {};
  int n0s = ks * (NN / 8);
  for (int n0 = n0s; n0 < n0s + NN / 8; n0 += 16) {
    int cc = tid & 63, kk0 = tid >> 6;
#pragma unroll
    for (int i = 0; i < 4; ++i) {
      int kk = kk0 * 4 + i;
      size_t base = (size_t)(n0 + kk) * CC;
      Ks[kk][cc] = PKb[base + c0 + cc];
      Vs[kk][cc] = Vb[base + d0 + cc];
    }
    __syncthreads();
#pragma unroll
    for (int kk = 0; kk < 16; ++kk) {
      float kvv[4], vv[4];
#pragma unroll
      for (int a = 0; a < 4; ++a) kvv[a] = Ks[kk][ty * 4 + a];
#pragma unroll
      for (int c = 0; c < 4; ++c) vv[c] = Vs[kk][tx * 4 + c];
#pragma unroll
      for (int a = 0; a < 4; ++a)
#pragma unroll
        for (int c = 0; c < 4; ++c) acc[a][c] += kvv[a] * vv[c];
    }
    __syncthreads();
  }
#pragma unroll
  for (int a = 0; a < 4; ++a)
#pragma unroll
    for (int c = 0; c < 4; ++c)
      part[((size_t)blockIdx.z * CC + c0 + ty * 4 + a) * CC + d0 + tx * 4 + c] = acc[a][c];
}

// ---------- kvT[b][d][c] = sum_ks part[b*8+ks][c][d] ----------
__global__ __launch_bounds__(256) void kvred_kern(const float* __restrict__ part,
                                                  float* __restrict__ kvT) {
  int c = blockIdx.x, b = blockIdx.y, d = threadIdx.x;
  float s = 0.f;
#pragma unroll
  for (int ks = 0; ks < 8; ++ks)
    s += part[((size_t)(b * 8 + ks) * CC + c) * CC + d];
  kvT[((size_t)b * CC + d) * CC + c] = s;
}

// ---------- ksum[b][c] = sum_n phiK[b,n,c] ----------
__global__ __launch_bounds__(256) void csum_kern(const float* __restrict__ PK,
                                                 float* __restrict__ ksum) {
  int c = blockIdx.x, b = blockIdx.y, t = threadIdx.x;
  const float* PKb = PK + (size_t)b * NN * CC;
  float s = 0.f;
  for (int k = 0; k < 16; ++k) s += PKb[(size_t)(t + 256 * k) * CC + c];
  __shared__ float sa[256];
  sa[t] = s; __syncthreads();
  for (int st = 128; st > 0; st >>= 1) {
    if (t < st) sa[t] += sa[t + st];
    __syncthreads();
  }
  if (t == 0) ksum[b * CC + c] = sa[0];
}

// ---------- rden[b*NN+n] = 1/(phiQ[n,:].ksum[b,:] + eps) ----------
__global__ __launch_bounds__(256) void den_kern(const float* __restrict__ PQ,
                                                const float* __restrict__ ksum,
                                                float* __restrict__ rden) {
  int n = blockIdx.x, b = blockIdx.y, c = threadIdx.x;
  size_t m = (size_t)b * NN + n;
  __shared__ float sa[256];
  sa[c] = PQ[m * CC + c] * ksum[b * CC + c];
  __syncthreads();
  for (int st = 128; st > 0; st >>= 1) {
    if (c < st) sa[c] += sa[c + st];
    __syncthreads();
  }
  if (c == 0) rden[m] = 1.f / (sa[0] + 1e-5f);
}

// ---------- DyT (optional fused residual add) ----------
template <bool RESID>
__global__ __launch_bounds__(256) void dyt_kern(const float* __restrict__ X,
                                                const float* __restrict__ R,
                                                const float* __restrict__ g,
                                                const float* __restrict__ bt,
                                                float* __restrict__ T) {
  int m = blockIdx.x, c = threadIdx.x;
  size_t idx = (size_t)m * CC + c;
  float x = X[idx];
  if constexpr (RESID) x += R[idx];
  __shared__ float sa[256], qa[256];
  sa[c] = x; qa[c] = x * x;
  __syncthreads();
  for (int st = 128; st > 0; st >>= 1) {
    if (c < st) { sa[c] += sa[c + st]; qa[c] += qa[c + st]; }
    __syncthreads();
  }
  float sum = sa[0], sq = qa[0];
  float mu = sum * (1.f / 256.f);
  float var = (sq - 256.f * mu * mu) * (1.f / 255.f);
  float sd = sqrtf(fmaxf(var, 0.f)) + 1e-5f;
  T[idx] = tanhf(g[c] * (x - mu) / sd + bt[c]);
}

// ---------- pool[b][c] = sum_n T[b,n,c] ----------
__global__ __launch_bounds__(256) void pool_kern(const float* __restrict__ T,
                                                 float* __restrict__ pool) {
  int b = blockIdx.x, c = blockIdx.y, t = threadIdx.x;
  float s = 0.f;
  for (int k = 0; k < 16; ++k)
    s += T[((size_t)b * NN + t + 256 * k) * CC + c];
  __shared__ float sa[256];
  sa[t] = s; __syncthreads();
  for (int st = 128; st > 0; st >>= 1) {
    if (t < st) sa[t] += sa[t + st];
    __syncthreads();
  }
  if (t == 0) pool[b * CC + c] = sa[0];
}

// ---------- gate[b][o] = sigmoid(m_w . pool[b]/4096 + m_b) ----------
__global__ __launch_bounds__(256) void gate_kern(const float* __restrict__ pool,
                                                 const float* __restrict__ w,
                                                 const float* __restrict__ bias,
                                                 float* __restrict__ gate) {
  int b = blockIdx.x, o = threadIdx.x;
  __shared__ float p[CC];
  p[o] = pool[b * CC + o] * (1.f / 4096.f);
  __syncthreads();
  float s = bias[o];
  for (int c = 0; c < CC; ++c) s += p[c] * w[o * CC + c];
  gate[b * CC + o] = sigmf(s);
}

// ---------- O = T * gate[b][c] ----------
__global__ __launch_bounds__(256) void scale_kern(const float* __restrict__ T,
                                                  const float* __restrict__ gate,
                                                  float* __restrict__ O_) {
  size_t i = (size_t)blockIdx.x * 256 + threadIdx.x;
  int b = (int)(i >> 20);
  int c = (int)(i & (CC - 1));
  O_[i] = T[i] * gate[b * CC + c];
}

// ---------- depthwise 3x3 + act, batched ----------
template <int CHN, int ACT>  // ACT 0=sigmoid 1=gelu
__global__ __launch_bounds__(256) void dwconv_kern(const float* __restrict__ X,
                                                   const float* __restrict__ w,
                                                   const float* __restrict__ bias,
                                                   float* __restrict__ Y) {
  int b = blockIdx.z;
  const float* Xb = X + (size_t)b * NN * CHN;
  float* Yb       = Y + (size_t)b * NN * CHN;
  int c = blockIdx.x * 64 + (threadIdx.x & 63);
  int yy = blockIdx.y;
  int xq = threadIdx.x >> 6;
  float wr[9];
#pragma unroll
  for (int j = 0; j < 9; ++j) wr[j] = w[c * 9 + j];
  float bb = bias[c];
  for (int x0 = xq; x0 < HW; x0 += 4) {
    float acc = bb;
#pragma unroll
    for (int ky = 0; ky < 3; ++ky) {
      int y2 = yy + ky - 1;
      if (y2 < 0 || y2 >= HW) continue;
#pragma unroll
      for (int kx = 0; kx < 3; ++kx) {
        int x2 = x0 + kx - 1;
        if (x2 < 0 || x2 >= HW) continue;
        acc += Xb[((size_t)y2 * HW + x2) * CHN + c] * wr[ky * 3 + kx];
      }
    }
    Yb[((size_t)yy * HW + x0) * CHN + c] = (ACT == 0) ? sigmf(acc) : geluf(acc);
  }
}

extern "C" void kernel_launch(void* const* d_in, const int* in_sizes, int n_in,
                              void* d_out, int out_size, void* d_ws, size_t ws_size,
                              hipStream_t stream) {
  (void)in_sizes; (void)n_in; (void)out_size; (void)ws_size;
  const float* x       = (const float*)d_in[0];
  const float* in_proj = (const float*)d_in[1];
  const float* wq_w = (const float*)d_in[2];   const float* wq_b = (const float*)d_in[3];
  const float* wk_w = (const float*)d_in[4];   const float* wk_b = (const float*)d_in[5];
  const float* wv_w = (const float*)d_in[6];   const float* wv_b = (const float*)d_in[7];
  const float* wo_w = (const float*)d_in[8];   const float* wo_b = (const float*)d_in[9];
  const float* psi_w = (const float*)d_in[10]; const float* psi_b = (const float*)d_in[11];
  const float* dyt_g = (const float*)d_in[12]; const float* dyt_b = (const float*)d_in[13];
  const float* m1_w = (const float*)d_in[14];  const float* m1_b = (const float*)d_in[15];
  const float* m2_w = (const float*)d_in[16];  const float* m2_b = (const float*)d_in[17];
  const float* we_w = (const float*)d_in[18];  const float* we_b = (const float*)d_in[19];
  const float* dw_w = (const float*)d_in[20];  const float* dw_b = (const float*)d_in[21];
  const float* wp_w = (const float*)d_in[22];  const float* wp_b = (const float*)d_in[23];
  const float* wout = (const float*)d_in[24];
  float* out = (float*)d_out;

  char* ws = (char*)d_ws;
  const size_t MB = 1u << 20;
  float* H    = (float*)(ws);               // h -> U1
  float* A    = (float*)(ws + 32 * MB);     // a -> U2 -> Y
  float* psiB = (float*)(ws + 64 * MB);     // psi -> num ; later e1 (2-batch)
  float* phiQ = (float*)(ws + 96 * MB);     // later e2
  float* phiK = (float*)(ws + 128 * MB);    // later T (dyt out)
  float* Vb   = (float*)(ws + 160 * MB);
  float* numb = psiB;
  float* e1   = psiB;
  float* e2   = phiQ;
  float* T    = phiK;
  float* kvpart = (float*)(ws + 192 * MB);  // 16 MiB [64][C][C]
  float* kvT    = (float*)(ws + 208 * MB);  // 2 MiB [B][C][C]
  float* pose   = (float*)(ws + 210 * MB);  // 4 MiB
  char*  small  = ws + 214 * MB;
  float* ksum  = (float*)(small);
  float* rden  = (float*)(small + 64 * 1024);    // 128 KiB
  float* pool1 = (float*)(small + 256 * 1024);
  float* pool2 = (float*)(small + 272 * 1024);
  float* gate1 = (float*)(small + 288 * 1024);
  float* gate2 = (float*)(small + 304 * 1024);

  dim3 blk(256);
  const size_t NC = (size_t)NN * CC;

  pos_kern<<<dim3(NN), blk, 0, stream>>>(pose);
  inproj_tile<<<dim3(64, 4, BB), blk, 0, stream>>>(x, in_proj, H);

  // ---- attention (batched, f32 — unchanged from R7) ----
  dwconv_kern<256, 0><<<dim3(4, 64, BB), blk, 0, stream>>>(H, psi_w, psi_b, psiB);
  gemm_tile<EPI_QK, false><<<dim3(64, 4, BB), blk, 0, stream>>>(H, wq_w, wq_b, phiQ, CC, CC, psiB, pose);
  gemm_tile<EPI_QK, false><<<dim3(64, 4, BB), blk, 0, stream>>>(H, wk_w, wk_b, phiK, CC, CC, psiB, pose);
  gemm_tile<EPI_BIAS, false><<<dim3(64, 4, BB), blk, 0, stream>>>(H, wv_w, wv_b, Vb, CC, CC, nullptr, nullptr);
  kvpart_kern<<<dim3(4, 4, 64), blk, 0, stream>>>(phiK, Vb, kvpart);
  kvred_kern<<<dim3(CC, BB), blk, 0, stream>>>(kvpart, kvT);
  csum_kern<<<dim3(CC, BB), blk, 0, stream>>>(phiK, ksum);
  den_kern<<<dim3(NN, BB), blk, 0, stream>>>(phiQ, ksum, rden);
  gemm_tile<EPI_NUM, true><<<dim3(64, 4, BB), blk, 0, stream>>>(phiQ, kvT, nullptr, numb, CC, CC, rden, nullptr);
  gemm_tile<EPI_BIAS, false><<<dim3(64, 4, BB), blk, 0, stream>>>(numb, wo_w, wo_b, A, CC, CC, nullptr, nullptr);

  // ---- U1 = mona1(dyt(h + a)) ----
  dyt_kern<true><<<dim3(MM), blk, 0, stream>>>(H, A, dyt_g, dyt_b, T);
  pool_kern<<<dim3(BB, CC), blk, 0, stream>>>(T, pool1);
  gate_kern<<<dim3(BB), blk, 0, stream>>>(pool1, m1_w, m1_b, gate1);
  scale_kern<<<dim3(MM), blk, 0, stream>>>(T, gate1, H);   // H = U1

  // ---- EDFFN, 2 batches per iteration — GEMMs now on the MFMA core ----
  for (int p = 0; p < 4; ++p) {
    const float* u1p = H + (size_t)(2 * p) * NC;
    float* u2p       = A + (size_t)(2 * p) * NC;
    // we: [8192,256] x [1024,256] -> [8192,1024]
    gemm_mfma<0><<<dim3(64, 8), blk, 0, stream>>>(u1p, we_w, we_b, e1, CC, DH, nullptr);
    dwconv_kern<1024, 1><<<dim3(16, 64, 2), blk, 0, stream>>>(e1, dw_w, dw_b, e2);
    // wp: [8192,1024] x [256,1024] -> [8192,256], +bias +2*U1
    gemm_mfma<1><<<dim3(64, 2), blk, 0, stream>>>(e2, wp_w, wp_b, u2p, DH, CC, u1p);
  }

  // ---- Y = mona2(dyt(U2)) ----
  dyt_kern<false><<<dim3(MM), blk, 0, stream>>>(A, nullptr, dyt_g, dyt_b, T);
  pool_kern<<<dim3(BB, CC), blk, 0, stream>>>(T, pool2);
  gate_kern<<<dim3(BB), blk, 0, stream>>>(pool2, m2_w, m2_b, gate2);
  scale_kern<<<dim3(MM), blk, 0, stream>>>(T, gate2, A);   // A = Y

  // ---- out_proj + SiLU, transposed write ----
  gemm_tile<EPI_OUT, false><<<dim3(64, 1, BB), blk, 0, stream>>>(A, wout, nullptr, out, CC, CIN, nullptr, nullptr);
}

// Round 10
// 1111.391 us; speedup vs baseline: 3.3077x; 1.1103x over previous
//
#include <hip/hip_runtime.h>
#include <hip/hip_bf16.h>
#include <cmath>

using bf16 = __hip_bfloat16;
using bf16x8 = __attribute__((ext_vector_type(8))) short;
using f32x4v = __attribute__((ext_vector_type(4))) float;

static constexpr int BB  = 8;
static constexpr int HW  = 64;
static constexpr int NN  = HW * HW;     // 4096
static constexpr int CC  = 256;
static constexpr int CIN = 64;
static constexpr int DH  = 1024;
static constexpr int MM  = BB * NN;     // 32768

__device__ __forceinline__ float siluf(float x) { return x / (1.f + expf(-x)); }
__device__ __forceinline__ float sigmf(float x) { return 1.f / (1.f + expf(-x)); }
__device__ __forceinline__ float geluf(float x) {
  float t = tanhf(0.7978845608028654f * (x + 0.044715f * x * x * x));
  return 0.5f * x * (1.f + t);
}

// ---------- pos table [N][C] ----------
__global__ __launch_bounds__(256) void pos_kern(float* __restrict__ pos) {
  int n = blockIdx.x, o = threadIdx.x;
  int yy = n >> 6, xx = n & 63;
  int i = o & 63, q = o >> 6;
  float omega = powf(10000.f, -(float)i / 64.f);
  float coord = (q < 2) ? (float)xx : (float)yy;
  float ang = coord * omega;
  pos[(size_t)n * CC + o] = (q & 1) ? cosf(ang) : sinf(ang);
}

// ---------- in_proj: NCHW(64ch) -> [B*N,256], tiled, + SiLU ----------
__global__ __launch_bounds__(256) void inproj_tile(const float* __restrict__ X,
                                                   const float* __restrict__ W,
                                                   float* __restrict__ H) {
  __shared__ float Xs[16][68];
  __shared__ float Ws[16][68];
  int m0 = blockIdx.x * 64, o0 = blockIdx.y * 64, b = blockIdx.z;
  int tid = threadIdx.x, tx = tid & 15, ty = tid >> 4;
  float acc[4][4] = {};
  for (int k0 = 0; k0 < CIN; k0 += 16) {
    {
      int mm = tid & 63, kk0 = tid >> 6;
#pragma unroll
      for (int i = 0; i < 4; ++i) {
        int kk = kk0 * 4 + i;
        Xs[kk][mm] = X[((size_t)(b * CIN + k0 + kk)) * NN + m0 + mm];
      }
    }
    {
      int kk = tid & 15, oo0 = tid >> 4;
#pragma unroll
      for (int i = 0; i < 4; ++i) {
        int oo = oo0 + i * 16;
        Ws[kk][oo] = W[(size_t)(o0 + oo) * CIN + k0 + kk];
      }
    }
    __syncthreads();
#pragma unroll
    for (int kk = 0; kk < 16; ++kk) {
      float xv[4], wv[4];
#pragma unroll
      for (int a = 0; a < 4; ++a) xv[a] = Xs[kk][ty * 4 + a];
#pragma unroll
      for (int c = 0; c < 4; ++c) wv[c] = Ws[kk][tx * 4 + c];
#pragma unroll
      for (int a = 0; a < 4; ++a)
#pragma unroll
        for (int c = 0; c < 4; ++c) acc[a][c] += xv[a] * wv[c];
    }
    __syncthreads();
  }
#pragma unroll
  for (int a = 0; a < 4; ++a) {
    int m = m0 + ty * 4 + a;
#pragma unroll
    for (int c = 0; c < 4; ++c) {
      int o = o0 + tx * 4 + c;
      H[((size_t)b * NN + m) * CC + o] = siluf(acc[a][c]);
    }
  }
}

// ---------- f32 tiled GEMM (kept for out_proj only) ----------
__global__ __launch_bounds__(256) void outproj_tile(const float* __restrict__ X,
                                                    const float* __restrict__ W,
                                                    float* __restrict__ Y) {
  __shared__ float Xs[16][68];
  __shared__ float Ws[16][68];
  int n0 = blockIdx.x * 64, b = blockIdx.z;
  size_t mbase = (size_t)b * NN;
  int tid = threadIdx.x, tx = tid & 15, ty = tid >> 4;
  float acc[4][4] = {};
  for (int k0 = 0; k0 < CC; k0 += 16) {
    int kk = tid & 15, rr0 = tid >> 4;
#pragma unroll
    for (int i = 0; i < 4; ++i) {
      int rr = rr0 + i * 16;
      Xs[kk][rr] = X[(mbase + n0 + rr) * CC + k0 + kk];
      Ws[kk][rr] = (rr < CIN) ? W[(size_t)rr * CC + k0 + kk] : 0.f;
    }
    __syncthreads();
#pragma unroll
    for (int kk2 = 0; kk2 < 16; ++kk2) {
      float xv[4], wv[4];
#pragma unroll
      for (int a = 0; a < 4; ++a) xv[a] = Xs[kk2][ty * 4 + a];
#pragma unroll
      for (int c = 0; c < 4; ++c) wv[c] = Ws[kk2][tx * 4 + c];
#pragma unroll
      for (int a = 0; a < 4; ++a)
#pragma unroll
        for (int c = 0; c < 4; ++c) acc[a][c] += xv[a] * wv[c];
    }
    __syncthreads();
  }
#pragma unroll
  for (int a = 0; a < 4; ++a) {
    int n = n0 + ty * 4 + a;
#pragma unroll
    for (int c = 0; c < 4; ++c) {
      int o = tx * 4 + c;
      if (o < CIN)
        Y[(size_t)(b * CIN + o) * NN + n] = siluf(acc[a][c]);
    }
  }
}

// ---------- bf16-MFMA GEMM core (verified R9), f32 in/out, fused epilogues ----------
// Y[m,o] = epi( sum_k X[m,k] * W[o,k] )
enum { EPI_PLAIN = 0, EPI_BIAS = 1, EPI_QK = 2, EPI_QKT = 3, EPI_BIAST = 4,
       EPI_NUM = 5, EPI_RESID = 6 };

__device__ __forceinline__ bf16x8 pack8(const float* s) {
  union { bf16x8 v; bf16 e[8]; } u;
#pragma unroll
  for (int i = 0; i < 8; ++i) u.e[i] = __float2bfloat16(s[i]);
  return u.v;
}

template <int EPI, bool WPB, bool KV>
__global__ __launch_bounds__(256) void gemm_mfma(const float* __restrict__ X,
                                                 const float* __restrict__ W,
                                                 const float* __restrict__ bias,
                                                 float* __restrict__ Y, int Kd, int Od,
                                                 const float* __restrict__ aux1,   // pose | rden
                                                 const float* __restrict__ aux2) { // psi | U1
  __shared__ bf16 As[128 * 32];
  __shared__ bf16 Bs[128 * 32];
  int m0 = blockIdx.x * 128, o0 = blockIdx.y * 128;
  if (KV) {                                  // per-batch kv GEMM
    size_t off = (size_t)blockIdx.z * CC * Kd;
    X += off; W += off;
    Y += (size_t)blockIdx.z * CC * CC;
  }
  const float* Wp = WPB ? (W + (size_t)(m0 >> 12) * Kd * Od) : W;
  int t = threadIdx.x;
  int l = t & 63, w = t >> 6;
  int wm = (w >> 1) * 64, wn = (w & 1) * 64;
  int lr = l & 15, lq = l >> 4;
  f32x4v acc[4][4] = {};
  for (int k0 = 0; k0 < Kd; k0 += 32) {
#pragma unroll
    for (int j = 0; j < 2; ++j) {
      int chunk = j * 256 + t;       // 0..511
      int row = chunk >> 2;          // 0..127
      int kc = (chunk & 3) * 8;
      float xs[8], wsv[8];
      const float* xp = X + (size_t)(m0 + row) * Kd + k0 + kc;
      const float* wp = Wp + (size_t)(o0 + row) * Kd + k0 + kc;
#pragma unroll
      for (int i = 0; i < 8; ++i) { xs[i] = xp[i]; wsv[i] = wp[i]; }
      *(bf16x8*)(As + row * 32 + kc) = pack8(xs);
      *(bf16x8*)(Bs + row * 32 + kc) = pack8(wsv);
    }
    __syncthreads();
    bf16x8 af[4], bfr[4];
#pragma unroll
    for (int mt = 0; mt < 4; ++mt)
      af[mt] = *(const bf16x8*)(As + (wm + mt * 16 + lr) * 32 + lq * 8);
#pragma unroll
    for (int nt = 0; nt < 4; ++nt)
      bfr[nt] = *(const bf16x8*)(Bs + (wn + nt * 16 + lr) * 32 + lq * 8);
#pragma unroll
    for (int mt = 0; mt < 4; ++mt)
#pragma unroll
      for (int nt = 0; nt < 4; ++nt)
        acc[mt][nt] = __builtin_amdgcn_mfma_f32_16x16x32_bf16(af[mt], bfr[nt], acc[mt][nt], 0, 0, 0);
    __syncthreads();
  }
  // C/D: col = lane&15 (o), row = (lane>>4)*4 + reg (m)   [verified R9]
#pragma unroll
  for (int nt = 0; nt < 4; ++nt) {
    int o = o0 + wn + nt * 16 + lr;
    float bv = (EPI == EPI_PLAIN || EPI == EPI_NUM) ? 0.f : bias[o];
#pragma unroll
    for (int mt = 0; mt < 4; ++mt) {
      int mb = m0 + wm + mt * 16 + lq * 4;
#pragma unroll
      for (int r = 0; r < 4; ++r) {
        int m = mb + r;
        float v = acc[mt][nt][r] + bv;
        if constexpr (EPI == EPI_PLAIN || EPI == EPI_BIAS) {
          Y[(size_t)m * Od + o] = v;
        } else if constexpr (EPI == EPI_QK || EPI == EPI_QKT) {
          int n = m & (NN - 1), b = m >> 12;
          v = (v + aux1[(size_t)n * CC + o]) * aux2[(size_t)m * CC + o];
          v = fmaxf(v, 0.f);
          v = v * v;
          if constexpr (EPI == EPI_QK)
            Y[(size_t)m * Od + o] = v;
          else
            Y[((size_t)(b * CC + o)) * NN + n] = v;   // phiKT[b][c][n]
        } else if constexpr (EPI == EPI_BIAST) {
          int n = m & (NN - 1), b = m >> 12;
          Y[((size_t)(b * CC + o)) * NN + n] = v;     // VT[b][d][n]
        } else if constexpr (EPI == EPI_NUM) {
          Y[(size_t)m * Od + o] = v * aux1[m];
        } else {  // EPI_RESID
          Y[(size_t)m * Od + o] = v + 2.f * aux2[(size_t)m * Od + o];
        }
      }
    }
  }
}

// ---------- ksum[b*CC+c] = sum_n phiKT[b][c][n]  (contiguous row sum) ----------
__global__ __launch_bounds__(256) void csumT_kern(const float* __restrict__ PKT,
                                                  float* __restrict__ ksum) {
  int bc = blockIdx.x;
  const float* row = PKT + (size_t)bc * NN;
  int t = threadIdx.x;
  float s = 0.f;
  for (int k = t; k < NN; k += 256) s += row[k];
  __shared__ float sa[256];
  sa[t] = s; __syncthreads();
  for (int st = 128; st > 0; st >>= 1) {
    if (t < st) sa[t] += sa[t + st];
    __syncthreads();
  }
  if (t == 0) ksum[bc] = sa[0];
}

// ---------- rden[b*NN+n] = 1/(phiQ[n,:].ksum[b,:] + eps) ----------
__global__ __launch_bounds__(256) void den_kern(const float* __restrict__ PQ,
                                                const float* __restrict__ ksum,
                                                float* __restrict__ rden) {
  int n = blockIdx.x, b = blockIdx.y, c = threadIdx.x;
  size_t m = (size_t)b * NN + n;
  __shared__ float sa[256];
  sa[c] = PQ[m * CC + c] * ksum[b * CC + c];
  __syncthreads();
  for (int st = 128; st > 0; st >>= 1) {
    if (c < st) sa[c] += sa[c + st];
    __syncthreads();
  }
  if (c == 0) rden[m] = 1.f / (sa[0] + 1e-5f);
}

// ---------- DyT (optional fused residual add) ----------
template <bool RESID>
__global__ __launch_bounds__(256) void dyt_kern(const float* __restrict__ X,
                                                const float* __restrict__ R,
                                                const float* __restrict__ g,
                                                const float* __restrict__ bt,
                                                float* __restrict__ T) {
  int m = blockIdx.x, c = threadIdx.x;
  size_t idx = (size_t)m * CC + c;
  float x = X[idx];
  if constexpr (RESID) x += R[idx];
  __shared__ float sa[256], qa[256];
  sa[c] = x; qa[c] = x * x;
  __syncthreads();
  for (int st = 128; st > 0; st >>= 1) {
    if (c < st) { sa[c] += sa[c + st]; qa[c] += qa[c + st]; }
    __syncthreads();
  }
  float sum = sa[0], sq = qa[0];
  float mu = sum * (1.f / 256.f);
  float var = (sq - 256.f * mu * mu) * (1.f / 255.f);
  float sd = sqrtf(fmaxf(var, 0.f)) + 1e-5f;
  T[idx] = tanhf(g[c] * (x - mu) / sd + bt[c]);
}

// ---------- pool[b][c] = sum_n T[b,n,c] ----------
__global__ __launch_bounds__(256) void pool_kern(const float* __restrict__ T,
                                                 float* __restrict__ pool) {
  int b = blockIdx.x, c = blockIdx.y, t = threadIdx.x;
  float s = 0.f;
  for (int k = 0; k < 16; ++k)
    s += T[((size_t)b * NN + t + 256 * k) * CC + c];
  __shared__ float sa[256];
  sa[t] = s; __syncthreads();
  for (int st = 128; st > 0; st >>= 1) {
    if (t < st) sa[t] += sa[t + st];
    __syncthreads();
  }
  if (t == 0) pool[b * CC + c] = sa[0];
}

// ---------- gate[b][o] = sigmoid(m_w . pool[b]/4096 + m_b) ----------
__global__ __launch_bounds__(256) void gate_kern(const float* __restrict__ pool,
                                                 const float* __restrict__ w,
                                                 const float* __restrict__ bias,
                                                 float* __restrict__ gate) {
  int b = blockIdx.x, o = threadIdx.x;
  __shared__ float p[CC];
  p[o] = pool[b * CC + o] * (1.f / 4096.f);
  __syncthreads();
  float s = bias[o];
  for (int c = 0; c < CC; ++c) s += p[c] * w[o * CC + c];
  gate[b * CC + o] = sigmf(s);
}

// ---------- O = T * gate[b][c] ----------
__global__ __launch_bounds__(256) void scale_kern(const float* __restrict__ T,
                                                  const float* __restrict__ gate,
                                                  float* __restrict__ O_) {
  size_t i = (size_t)blockIdx.x * 256 + threadIdx.x;
  int b = (int)(i >> 20);
  int c = (int)(i & (CC - 1));
  O_[i] = T[i] * gate[b * CC + c];
}

// ---------- depthwise 3x3 + act, batched ----------
template <int CHN, int ACT>  // ACT 0=sigmoid 1=gelu
__global__ __launch_bounds__(256) void dwconv_kern(const float* __restrict__ X,
                                                   const float* __restrict__ w,
                                                   const float* __restrict__ bias,
                                                   float* __restrict__ Y) {
  int b = blockIdx.z;
  const float* Xb = X + (size_t)b * NN * CHN;
  float* Yb       = Y + (size_t)b * NN * CHN;
  int c = blockIdx.x * 64 + (threadIdx.x & 63);
  int yy = blockIdx.y;
  int xq = threadIdx.x >> 6;
  float wr[9];
#pragma unroll
  for (int j = 0; j < 9; ++j) wr[j] = w[c * 9 + j];
  float bb = bias[c];
  for (int x0 = xq; x0 < HW; x0 += 4) {
    float acc = bb;
#pragma unroll
    for (int ky = 0; ky < 3; ++ky) {
      int y2 = yy + ky - 1;
      if (y2 < 0 || y2 >= HW) continue;
#pragma unroll
      for (int kx = 0; kx < 3; ++kx) {
        int x2 = x0 + kx - 1;
        if (x2 < 0 || x2 >= HW) continue;
        acc += Xb[((size_t)y2 * HW + x2) * CHN + c] * wr[ky * 3 + kx];
      }
    }
    Yb[((size_t)yy * HW + x0) * CHN + c] = (ACT == 0) ? sigmf(acc) : geluf(acc);
  }
}

extern "C" void kernel_launch(void* const* d_in, const int* in_sizes, int n_in,
                              void* d_out, int out_size, void* d_ws, size_t ws_size,
                              hipStream_t stream) {
  (void)in_sizes; (void)n_in; (void)out_size; (void)ws_size;
  const float* x       = (const float*)d_in[0];
  const float* in_proj = (const float*)d_in[1];
  const float* wq_w = (const float*)d_in[2];   const float* wq_b = (const float*)d_in[3];
  const float* wk_w = (const float*)d_in[4];   const float* wk_b = (const float*)d_in[5];
  const float* wv_w = (const float*)d_in[6];   const float* wv_b = (const float*)d_in[7];
  const float* wo_w = (const float*)d_in[8];   const float* wo_b = (const float*)d_in[9];
  const float* psi_w = (const float*)d_in[10]; const float* psi_b = (const float*)d_in[11];
  const float* dyt_g = (const float*)d_in[12]; const float* dyt_b = (const float*)d_in[13];
  const float* m1_w = (const float*)d_in[14];  const float* m1_b = (const float*)d_in[15];
  const float* m2_w = (const float*)d_in[16];  const float* m2_b = (const float*)d_in[17];
  const float* we_w = (const float*)d_in[18];  const float* we_b = (const float*)d_in[19];
  const float* dw_w = (const float*)d_in[20];  const float* dw_b = (const float*)d_in[21];
  const float* wp_w = (const float*)d_in[22];  const float* wp_b = (const float*)d_in[23];
  const float* wout = (const float*)d_in[24];
  float* out = (float*)d_out;

  char* ws = (char*)d_ws;
  const size_t MB = 1u << 20;
  float* H     = (float*)(ws);               // h -> U1
  float* A     = (float*)(ws + 32 * MB);     // a -> U2 -> Y
  float* psiB  = (float*)(ws + 64 * MB);     // psi -> num ; later e1
  float* phiQ  = (float*)(ws + 96 * MB);     // later e2
  float* phiKT = (float*)(ws + 128 * MB);    // [B][C][N]; later T (dyt out)
  float* VT    = (float*)(ws + 160 * MB);    // [B][C][N]
  float* numb  = psiB;
  float* e1    = psiB;
  float* e2    = phiQ;
  float* T     = phiKT;
  float* kvT   = (float*)(ws + 208 * MB);    // 2 MiB [B][C][C]
  float* pose  = (float*)(ws + 210 * MB);    // 4 MiB
  char*  small = ws + 214 * MB;
  float* ksum  = (float*)(small);
  float* rden  = (float*)(small + 64 * 1024);    // 128 KiB
  float* pool1 = (float*)(small + 256 * 1024);
  float* pool2 = (float*)(small + 272 * 1024);
  float* gate1 = (float*)(small + 288 * 1024);
  float* gate2 = (float*)(small + 304 * 1024);

  dim3 blk(256);
  const size_t NC = (size_t)NN * CC;

  pos_kern<<<dim3(NN), blk, 0, stream>>>(pose);
  inproj_tile<<<dim3(64, 4, BB), blk, 0, stream>>>(x, in_proj, H);

  // ---- attention (all MFMA) ----
  dwconv_kern<256, 0><<<dim3(4, 64, BB), blk, 0, stream>>>(H, psi_w, psi_b, psiB);
  gemm_mfma<EPI_QK, false, false><<<dim3(256, 2), blk, 0, stream>>>(H, wq_w, wq_b, phiQ, CC, CC, pose, psiB);
  gemm_mfma<EPI_QKT, false, false><<<dim3(256, 2), blk, 0, stream>>>(H, wk_w, wk_b, phiKT, CC, CC, pose, psiB);
  gemm_mfma<EPI_BIAST, false, false><<<dim3(256, 2), blk, 0, stream>>>(H, wv_w, wv_b, VT, CC, CC, nullptr, nullptr);
  // kvT[b][d][c] = sum_n VT[b,d,n] * phiKT[b,c,n]
  gemm_mfma<EPI_PLAIN, false, true><<<dim3(2, 2, BB), blk, 0, stream>>>(VT, phiKT, nullptr, kvT, NN, CC, nullptr, nullptr);
  csumT_kern<<<dim3(BB * CC), blk, 0, stream>>>(phiKT, ksum);
  den_kern<<<dim3(NN, BB), blk, 0, stream>>>(phiQ, ksum, rden);
  gemm_mfma<EPI_NUM, true, false><<<dim3(256, 2), blk, 0, stream>>>(phiQ, kvT, nullptr, numb, CC, CC, rden, nullptr);
  gemm_mfma<EPI_BIAS, false, false><<<dim3(256, 2), blk, 0, stream>>>(numb, wo_w, wo_b, A, CC, CC, nullptr, nullptr);

  // ---- U1 = mona1(dyt(h + a)) ----
  dyt_kern<true><<<dim3(MM), blk, 0, stream>>>(H, A, dyt_g, dyt_b, T);
  pool_kern<<<dim3(BB, CC), blk, 0, stream>>>(T, pool1);
  gate_kern<<<dim3(BB), blk, 0, stream>>>(pool1, m1_w, m1_b, gate1);
  scale_kern<<<dim3(MM), blk, 0, stream>>>(T, gate1, H);   // H = U1

  // ---- EDFFN (R9 verbatim), 2 batches per iteration ----
  for (int p = 0; p < 4; ++p) {
    const float* u1p = H + (size_t)(2 * p) * NC;
    float* u2p       = A + (size_t)(2 * p) * NC;
    gemm_mfma<EPI_BIAS, false, false><<<dim3(64, 8), blk, 0, stream>>>(u1p, we_w, we_b, e1, CC, DH, nullptr, nullptr);
    dwconv_kern<1024, 1><<<dim3(16, 64, 2), blk, 0, stream>>>(e1, dw_w, dw_b, e2);
    gemm_mfma<EPI_RESID, false, false><<<dim3(64, 2), blk, 0, stream>>>(e2, wp_w, wp_b, u2p, DH, CC, nullptr, u1p);
  }

  // ---- Y = mona2(dyt(U2)) ----
  dyt_kern<false><<<dim3(MM), blk, 0, stream>>>(A, nullptr, dyt_g, dyt_b, T);
  pool_kern<<<dim3(BB, CC), blk, 0, stream>>>(T, pool2);
  gate_kern<<<dim3(BB), blk, 0, stream>>>(pool2, m2_w, m2_b, gate2);
  scale_kern<<<dim3(MM), blk, 0, stream>>>(T, gate2, A);   // A = Y

  // ---- out_proj + SiLU, transposed write ----
  outproj_tile<<<dim3(64, 1, BB), blk, 0, stream>>>(A, wout, out);
}

// Round 11
// 943.279 us; speedup vs baseline: 3.8972x; 1.1782x over previous
//
#include <hip/hip_runtime.h>
#include <hip/hip_bf16.h>
#include <cmath>

using bf16 = __hip_bfloat16;
using bf16x8 = __attribute__((ext_vector_type(8))) short;
using f32x4v = __attribute__((ext_vector_type(4))) float;

static constexpr int BB  = 8;
static constexpr int HW  = 64;
static constexpr int NN  = HW * HW;     // 4096
static constexpr int CC  = 256;
static constexpr int CIN = 64;
static constexpr int DH  = 1024;
static constexpr int MM  = BB * NN;     // 32768

__device__ __forceinline__ float siluf(float x) { return x / (1.f + expf(-x)); }
__device__ __forceinline__ float sigmf(float x) { return 1.f / (1.f + expf(-x)); }
__device__ __forceinline__ float geluf(float x) {
  float t = tanhf(0.7978845608028654f * (x + 0.044715f * x * x * x));
  return 0.5f * x * (1.f + t);
}

// ---------- pos table [N][C] ----------
__global__ __launch_bounds__(256) void pos_kern(float* __restrict__ pos) {
  int n = blockIdx.x, o = threadIdx.x;
  int yy = n >> 6, xx = n & 63;
  int i = o & 63, q = o >> 6;
  float omega = powf(10000.f, -(float)i / 64.f);
  float coord = (q < 2) ? (float)xx : (float)yy;
  float ang = coord * omega;
  pos[(size_t)n * CC + o] = (q & 1) ? cosf(ang) : sinf(ang);
}

// ---------- in_proj: NCHW(64ch) -> [B*N,256], tiled, + SiLU ----------
__global__ __launch_bounds__(256) void inproj_tile(const float* __restrict__ X,
                                                   const float* __restrict__ W,
                                                   float* __restrict__ H) {
  __shared__ float Xs[16][68];
  __shared__ float Ws[16][68];
  int m0 = blockIdx.x * 64, o0 = blockIdx.y * 64, b = blockIdx.z;
  int tid = threadIdx.x, tx = tid & 15, ty = tid >> 4;
  float acc[4][4] = {};
  for (int k0 = 0; k0 < CIN; k0 += 16) {
    {
      int mm = tid & 63, kk0 = tid >> 6;
#pragma unroll
      for (int i = 0; i < 4; ++i) {
        int kk = kk0 * 4 + i;
        Xs[kk][mm] = X[((size_t)(b * CIN + k0 + kk)) * NN + m0 + mm];
      }
    }
    {
      int kk = tid & 15, oo0 = tid >> 4;
#pragma unroll
      for (int i = 0; i < 4; ++i) {
        int oo = oo0 + i * 16;
        Ws[kk][oo] = W[(size_t)(o0 + oo) * CIN + k0 + kk];
      }
    }
    __syncthreads();
#pragma unroll
    for (int kk = 0; kk < 16; ++kk) {
      float xv[4], wv[4];
#pragma unroll
      for (int a = 0; a < 4; ++a) xv[a] = Xs[kk][ty * 4 + a];
#pragma unroll
      for (int c = 0; c < 4; ++c) wv[c] = Ws[kk][tx * 4 + c];
#pragma unroll
      for (int a = 0; a < 4; ++a)
#pragma unroll
        for (int c = 0; c < 4; ++c) acc[a][c] += xv[a] * wv[c];
    }
    __syncthreads();
  }
#pragma unroll
  for (int a = 0; a < 4; ++a) {
    int m = m0 + ty * 4 + a;
#pragma unroll
    for (int c = 0; c < 4; ++c) {
      int o = o0 + tx * 4 + c;
      H[((size_t)b * NN + m) * CC + o] = siluf(acc[a][c]);
    }
  }
}

// ---------- f32 tiled GEMM (kept for out_proj only) ----------
__global__ __launch_bounds__(256) void outproj_tile(const float* __restrict__ X,
                                                    const float* __restrict__ W,
                                                    float* __restrict__ Y) {
  __shared__ float Xs[16][68];
  __shared__ float Ws[16][68];
  int n0 = blockIdx.x * 64, b = blockIdx.z;
  size_t mbase = (size_t)b * NN;
  int tid = threadIdx.x, tx = tid & 15, ty = tid >> 4;
  float acc[4][4] = {};
  for (int k0 = 0; k0 < CC; k0 += 16) {
    int kk = tid & 15, rr0 = tid >> 4;
#pragma unroll
    for (int i = 0; i < 4; ++i) {
      int rr = rr0 + i * 16;
      Xs[kk][rr] = X[(mbase + n0 + rr) * CC + k0 + kk];
      Ws[kk][rr] = (rr < CIN) ? W[(size_t)rr * CC + k0 + kk] : 0.f;
    }
    __syncthreads();
#pragma unroll
    for (int kk2 = 0; kk2 < 16; ++kk2) {
      float xv[4], wv[4];
#pragma unroll
      for (int a = 0; a < 4; ++a) xv[a] = Xs[kk2][ty * 4 + a];
#pragma unroll
      for (int c = 0; c < 4; ++c) wv[c] = Ws[kk2][tx * 4 + c];
#pragma unroll
      for (int a = 0; a < 4; ++a)
#pragma unroll
        for (int c = 0; c < 4; ++c) acc[a][c] += xv[a] * wv[c];
    }
    __syncthreads();
  }
#pragma unroll
  for (int a = 0; a < 4; ++a) {
    int n = n0 + ty * 4 + a;
#pragma unroll
    for (int c = 0; c < 4; ++c) {
      int o = tx * 4 + c;
      if (o < CIN)
        Y[(size_t)(b * CIN + o) * NN + n] = siluf(acc[a][c]);
    }
  }
}

// ---------- bf16-MFMA GEMM core, f32 in/out, fused epilogues ----------
enum { EPI_PLAIN = 0, EPI_BIAS = 1, EPI_QK = 2, EPI_QKT = 3, EPI_BIAST = 4,
       EPI_NUM = 5, EPI_RESID = 6 };

__device__ __forceinline__ bf16x8 pack8(const float* s) {
  union { bf16x8 v; bf16 e[8]; } u;
#pragma unroll
  for (int i = 0; i < 8; ++i) u.e[i] = __float2bfloat16(s[i]);
  return u.v;
}

// KVS: per-batch split-8 kv mode (z = b*8+ks, k-range = ks-th eighth of Kd,
//      partial output slot z)
template <int EPI, bool WPB, bool KVS>
__global__ __launch_bounds__(256) void gemm_mfma(const float* __restrict__ X,
                                                 const float* __restrict__ W,
                                                 const float* __restrict__ bias,
                                                 float* __restrict__ Y, int Kd, int Od,
                                                 const float* __restrict__ aux1,   // pose | rden
                                                 const float* __restrict__ aux2) { // psi | U1
  __shared__ bf16 As[128 * 32];
  __shared__ bf16 Bs[128 * 32];
  int m0 = blockIdx.x * 128, o0 = blockIdx.y * 128;
  int kbeg = 0, kend = Kd;
  if (KVS) {
    int b = blockIdx.z >> 3, ks = blockIdx.z & 7;
    size_t off = (size_t)b * CC * Kd;
    X += off; W += off;
    Y += (size_t)blockIdx.z * CC * CC;
    kbeg = ks * (Kd / 8); kend = kbeg + Kd / 8;
  }
  const float* Wp = WPB ? (W + (size_t)(m0 >> 12) * Kd * Od) : W;
  int t = threadIdx.x;
  int l = t & 63, w = t >> 6;
  int wm = (w >> 1) * 64, wn = (w & 1) * 64;
  int lr = l & 15, lq = l >> 4;
  f32x4v acc[4][4] = {};
  for (int k0 = kbeg; k0 < kend; k0 += 32) {
#pragma unroll
    for (int j = 0; j < 2; ++j) {
      int chunk = j * 256 + t;       // 0..511
      int row = chunk >> 2;          // 0..127
      int kc = (chunk & 3) * 8;
      float xs[8], wsv[8];
      const float* xp = X + (size_t)(m0 + row) * Kd + k0 + kc;
      const float* wp = Wp + (size_t)(o0 + row) * Kd + k0 + kc;
#pragma unroll
      for (int i = 0; i < 8; ++i) { xs[i] = xp[i]; wsv[i] = wp[i]; }
      *(bf16x8*)(As + row * 32 + kc) = pack8(xs);
      *(bf16x8*)(Bs + row * 32 + kc) = pack8(wsv);
    }
    __syncthreads();
    bf16x8 af[4], bfr[4];
#pragma unroll
    for (int mt = 0; mt < 4; ++mt)
      af[mt] = *(const bf16x8*)(As + (wm + mt * 16 + lr) * 32 + lq * 8);
#pragma unroll
    for (int nt = 0; nt < 4; ++nt)
      bfr[nt] = *(const bf16x8*)(Bs + (wn + nt * 16 + lr) * 32 + lq * 8);
#pragma unroll
    for (int mt = 0; mt < 4; ++mt)
#pragma unroll
      for (int nt = 0; nt < 4; ++nt)
        acc[mt][nt] = __builtin_amdgcn_mfma_f32_16x16x32_bf16(af[mt], bfr[nt], acc[mt][nt], 0, 0, 0);
    __syncthreads();
  }
  // C/D: col = lane&15 (o), row = (lane>>4)*4 + reg (m)
#pragma unroll
  for (int nt = 0; nt < 4; ++nt) {
    int o = o0 + wn + nt * 16 + lr;
    float bv = (EPI == EPI_PLAIN || EPI == EPI_NUM) ? 0.f : bias[o];
#pragma unroll
    for (int mt = 0; mt < 4; ++mt) {
      int mb = m0 + wm + mt * 16 + lq * 4;
#pragma unroll
      for (int r = 0; r < 4; ++r) {
        int m = mb + r;
        float v = acc[mt][nt][r] + bv;
        if constexpr (EPI == EPI_PLAIN || EPI == EPI_BIAS) {
          Y[(size_t)m * Od + o] = v;
        } else if constexpr (EPI == EPI_QK || EPI == EPI_QKT) {
          int n = m & (NN - 1), b = m >> 12;
          v = (v + aux1[(size_t)n * CC + o]) * aux2[(size_t)m * CC + o];
          v = fmaxf(v, 0.f);
          v = v * v;
          if constexpr (EPI == EPI_QK)
            Y[(size_t)m * Od + o] = v;
          else
            Y[((size_t)(b * CC + o)) * NN + n] = v;   // phiKT[b][c][n]
        } else if constexpr (EPI == EPI_BIAST) {
          int n = m & (NN - 1), b = m >> 12;
          Y[((size_t)(b * CC + o)) * NN + n] = v;     // VT[b][d][n]
        } else if constexpr (EPI == EPI_NUM) {
          Y[(size_t)m * Od + o] = v * aux1[m];
        } else {  // EPI_RESID
          Y[(size_t)m * Od + o] = v + 2.f * aux2[(size_t)m * Od + o];
        }
      }
    }
  }
}

// ---------- kvT[b][d][c] = sum_ks kvpart[b*8+ks][d][c] ----------
__global__ __launch_bounds__(256) void kvred_kern(const float* __restrict__ part,
                                                  float* __restrict__ kvT) {
  int d = blockIdx.x, b = blockIdx.y, c = threadIdx.x;
  float s = 0.f;
#pragma unroll
  for (int ks = 0; ks < 8; ++ks)
    s += part[((size_t)(b * 8 + ks) * CC + d) * CC + c];
  kvT[((size_t)b * CC + d) * CC + c] = s;
}

// ---------- ksum[b*CC+c] = sum_n phiKT[b][c][n] ----------
__global__ __launch_bounds__(256) void csumT_kern(const float* __restrict__ PKT,
                                                  float* __restrict__ ksum) {
  int bc = blockIdx.x;
  const float* row = PKT + (size_t)bc * NN;
  int t = threadIdx.x;
  float s = 0.f;
  for (int k = t; k < NN; k += 256) s += row[k];
  __shared__ float sa[256];
  sa[t] = s; __syncthreads();
  for (int st = 128; st > 0; st >>= 1) {
    if (t < st) sa[t] += sa[t + st];
    __syncthreads();
  }
  if (t == 0) ksum[bc] = sa[0];
}

// ---------- rden[b*NN+n] = 1/(phiQ[n,:].ksum[b,:] + eps) ----------
__global__ __launch_bounds__(256) void den_kern(const float* __restrict__ PQ,
                                                const float* __restrict__ ksum,
                                                float* __restrict__ rden) {
  int n = blockIdx.x, b = blockIdx.y, c = threadIdx.x;
  size_t m = (size_t)b * NN + n;
  __shared__ float sa[256];
  sa[c] = PQ[m * CC + c] * ksum[b * CC + c];
  __syncthreads();
  for (int st = 128; st > 0; st >>= 1) {
    if (c < st) sa[c] += sa[c + st];
    __syncthreads();
  }
  if (c == 0) rden[m] = 1.f / (sa[0] + 1e-5f);
}

// ---------- DyT (optional fused residual add) ----------
template <bool RESID>
__global__ __launch_bounds__(256) void dyt_kern(const float* __restrict__ X,
                                                const float* __restrict__ R,
                                                const float* __restrict__ g,
                                                const float* __restrict__ bt,
                                                float* __restrict__ T) {
  int m = blockIdx.x, c = threadIdx.x;
  size_t idx = (size_t)m * CC + c;
  float x = X[idx];
  if constexpr (RESID) x += R[idx];
  __shared__ float sa[256], qa[256];
  sa[c] = x; qa[c] = x * x;
  __syncthreads();
  for (int st = 128; st > 0; st >>= 1) {
    if (c < st) { sa[c] += sa[c + st]; qa[c] += qa[c + st]; }
    __syncthreads();
  }
  float sum = sa[0], sq = qa[0];
  float mu = sum * (1.f / 256.f);
  float var = (sq - 256.f * mu * mu) * (1.f / 255.f);
  float sd = sqrtf(fmaxf(var, 0.f)) + 1e-5f;
  T[idx] = tanhf(g[c] * (x - mu) / sd + bt[c]);
}

// ---------- pool[b][c] = sum_n T[b,n,c] ----------
__global__ __launch_bounds__(256) void pool_kern(const float* __restrict__ T,
                                                 float* __restrict__ pool) {
  int b = blockIdx.x, c = blockIdx.y, t = threadIdx.x;
  float s = 0.f;
  for (int k = 0; k < 16; ++k)
    s += T[((size_t)b * NN + t + 256 * k) * CC + c];
  __shared__ float sa[256];
  sa[t] = s; __syncthreads();
  for (int st = 128; st > 0; st >>= 1) {
    if (t < st) sa[t] += sa[t + st];
    __syncthreads();
  }
  if (t == 0) pool[b * CC + c] = sa[0];
}

// ---------- gate[b][o] = sigmoid(m_w . pool[b]/4096 + m_b) ----------
__global__ __launch_bounds__(256) void gate_kern(const float* __restrict__ pool,
                                                 const float* __restrict__ w,
                                                 const float* __restrict__ bias,
                                                 float* __restrict__ gate) {
  int b = blockIdx.x, o = threadIdx.x;
  __shared__ float p[CC];
  p[o] = pool[b * CC + o] * (1.f / 4096.f);
  __syncthreads();
  float s = bias[o];
  for (int c = 0; c < CC; ++c) s += p[c] * w[o * CC + c];
  gate[b * CC + o] = sigmf(s);
}

// ---------- O = T * gate[b][c] ----------
__global__ __launch_bounds__(256) void scale_kern(const float* __restrict__ T,
                                                  const float* __restrict__ gate,
                                                  float* __restrict__ O_) {
  size_t i = (size_t)blockIdx.x * 256 + threadIdx.x;
  int b = (int)(i >> 20);
  int c = (int)(i & (CC - 1));
  O_[i] = T[i] * gate[b * CC + c];
}

// ---------- depthwise 3x3 + act, batched ----------
template <int CHN, int ACT>  // ACT 0=sigmoid 1=gelu
__global__ __launch_bounds__(256) void dwconv_kern(const float* __restrict__ X,
                                                   const float* __restrict__ w,
                                                   const float* __restrict__ bias,
                                                   float* __restrict__ Y) {
  int b = blockIdx.z;
  const float* Xb = X + (size_t)b * NN * CHN;
  float* Yb       = Y + (size_t)b * NN * CHN;
  int c = blockIdx.x * 64 + (threadIdx.x & 63);
  int yy = blockIdx.y;
  int xq = threadIdx.x >> 6;
  float wr[9];
#pragma unroll
  for (int j = 0; j < 9; ++j) wr[j] = w[c * 9 + j];
  float bb = bias[c];
  for (int x0 = xq; x0 < HW; x0 += 4) {
    float acc = bb;
#pragma unroll
    for (int ky = 0; ky < 3; ++ky) {
      int y2 = yy + ky - 1;
      if (y2 < 0 || y2 >= HW) continue;
#pragma unroll
      for (int kx = 0; kx < 3; ++kx) {
        int x2 = x0 + kx - 1;
        if (x2 < 0 || x2 >= HW) continue;
        acc += Xb[((size_t)y2 * HW + x2) * CHN + c] * wr[ky * 3 + kx];
      }
    }
    Yb[((size_t)yy * HW + x0) * CHN + c] = (ACT == 0) ? sigmf(acc) : geluf(acc);
  }
}

extern "C" void kernel_launch(void* const* d_in, const int* in_sizes, int n_in,
                              void* d_out, int out_size, void* d_ws, size_t ws_size,
                              hipStream_t stream) {
  (void)in_sizes; (void)n_in; (void)out_size; (void)ws_size;
  const float* x       = (const float*)d_in[0];
  const float* in_proj = (const float*)d_in[1];
  const float* wq_w = (const float*)d_in[2];   const float* wq_b = (const float*)d_in[3];
  const float* wk_w = (const float*)d_in[4];   const float* wk_b = (const float*)d_in[5];
  const float* wv_w = (const float*)d_in[6];   const float* wv_b = (const float*)d_in[7];
  const float* wo_w = (const float*)d_in[8];   const float* wo_b = (const float*)d_in[9];
  const float* psi_w = (const float*)d_in[10]; const float* psi_b = (const float*)d_in[11];
  const float* dyt_g = (const float*)d_in[12]; const float* dyt_b = (const float*)d_in[13];
  const float* m1_w = (const float*)d_in[14];  const float* m1_b = (const float*)d_in[15];
  const float* m2_w = (const float*)d_in[16];  const float* m2_b = (const float*)d_in[17];
  const float* we_w = (const float*)d_in[18];  const float* we_b = (const float*)d_in[19];
  const float* dw_w = (const float*)d_in[20];  const float* dw_b = (const float*)d_in[21];
  const float* wp_w = (const float*)d_in[22];  const float* wp_b = (const float*)d_in[23];
  const float* wout = (const float*)d_in[24];
  float* out = (float*)d_out;

  char* ws = (char*)d_ws;
  const size_t MB = 1u << 20;
  float* H     = (float*)(ws);               // h -> U1
  float* A     = (float*)(ws + 32 * MB);     // a -> U2 -> Y
  float* psiB  = (float*)(ws + 64 * MB);     // psi -> num ; later e1 (4-batch, 64 MiB)
  float* phiQ  = (float*)(ws + 96 * MB);
  float* phiKT = (float*)(ws + 128 * MB);    // [B][C][N]; later e2 low half / T1
  float* VT    = (float*)(ws + 160 * MB);    // [B][C][N]
  float* numb  = psiB;
  float* e1    = psiB;                        // 64 MiB: 64..128
  float* e2    = phiKT;                       // 64 MiB: 128..192
  float* T1    = phiKT;                       // dyt1 out (before EDFFN)
  float* T2    = psiB;                        // dyt2 out (after EDFFN)
  float* kvpart = (float*)(ws + 192 * MB);   // 16 MiB [64][C][C]
  float* kvT    = (float*)(ws + 208 * MB);   // 2 MiB [B][C][C]
  float* pose   = (float*)(ws + 210 * MB);   // 4 MiB
  char*  small  = ws + 214 * MB;
  float* ksum  = (float*)(small);
  float* rden  = (float*)(small + 64 * 1024);    // 128 KiB
  float* pool1 = (float*)(small + 256 * 1024);
  float* pool2 = (float*)(small + 272 * 1024);
  float* gate1 = (float*)(small + 288 * 1024);
  float* gate2 = (float*)(small + 304 * 1024);

  dim3 blk(256);
  const size_t NC = (size_t)NN * CC;

  pos_kern<<<dim3(NN), blk, 0, stream>>>(pose);
  inproj_tile<<<dim3(64, 4, BB), blk, 0, stream>>>(x, in_proj, H);

  // ---- attention (all MFMA) ----
  dwconv_kern<256, 0><<<dim3(4, 64, BB), blk, 0, stream>>>(H, psi_w, psi_b, psiB);
  gemm_mfma<EPI_QK, false, false><<<dim3(256, 2), blk, 0, stream>>>(H, wq_w, wq_b, phiQ, CC, CC, pose, psiB);
  gemm_mfma<EPI_QKT, false, false><<<dim3(256, 2), blk, 0, stream>>>(H, wk_w, wk_b, phiKT, CC, CC, pose, psiB);
  gemm_mfma<EPI_BIAST, false, false><<<dim3(256, 2), blk, 0, stream>>>(H, wv_w, wv_b, VT, CC, CC, nullptr, nullptr);
  // kv partials: kvpart[b*8+ks][d][c] = sum_{n in chunk} VT[b,d,n] * phiKT[b,c,n]
  gemm_mfma<EPI_PLAIN, false, true><<<dim3(2, 2, 64), blk, 0, stream>>>(VT, phiKT, nullptr, kvpart, NN, CC, nullptr, nullptr);
  kvred_kern<<<dim3(CC, BB), blk, 0, stream>>>(kvpart, kvT);
  csumT_kern<<<dim3(BB * CC), blk, 0, stream>>>(phiKT, ksum);
  den_kern<<<dim3(NN, BB), blk, 0, stream>>>(phiQ, ksum, rden);
  gemm_mfma<EPI_NUM, true, false><<<dim3(256, 2), blk, 0, stream>>>(phiQ, kvT, nullptr, numb, CC, CC, rden, nullptr);
  gemm_mfma<EPI_BIAS, false, false><<<dim3(256, 2), blk, 0, stream>>>(numb, wo_w, wo_b, A, CC, CC, nullptr, nullptr);

  // ---- U1 = mona1(dyt(h + a)) ----
  dyt_kern<true><<<dim3(MM), blk, 0, stream>>>(H, A, dyt_g, dyt_b, T1);
  pool_kern<<<dim3(BB, CC), blk, 0, stream>>>(T1, pool1);
  gate_kern<<<dim3(BB), blk, 0, stream>>>(pool1, m1_w, m1_b, gate1);
  scale_kern<<<dim3(MM), blk, 0, stream>>>(T1, gate1, H);   // H = U1

  // ---- EDFFN, 2 passes x 4 batches ----
  for (int p = 0; p < 2; ++p) {
    const float* u1p = H + (size_t)(4 * p) * NC;
    float* u2p       = A + (size_t)(4 * p) * NC;
    gemm_mfma<EPI_BIAS, false, false><<<dim3(128, 8), blk, 0, stream>>>(u1p, we_w, we_b, e1, CC, DH, nullptr, nullptr);
    dwconv_kern<1024, 1><<<dim3(16, 64, 4), blk, 0, stream>>>(e1, dw_w, dw_b, e2);
    gemm_mfma<EPI_RESID, false, false><<<dim3(128, 2), blk, 0, stream>>>(e2, wp_w, wp_b, u2p, DH, CC, nullptr, u1p);
  }

  // ---- Y = mona2(dyt(U2)) ----
  dyt_kern<false><<<dim3(MM), blk, 0, stream>>>(A, nullptr, dyt_g, dyt_b, T2);
  pool_kern<<<dim3(BB, CC), blk, 0, stream>>>(T2, pool2);
  gate_kern<<<dim3(BB), blk, 0, stream>>>(pool2, m2_w, m2_b, gate2);
  scale_kern<<<dim3(MM), blk, 0, stream>>>(T2, gate2, A);   // A = Y

  // ---- out_proj + SiLU, transposed write ----
  outproj_tile<<<dim3(64, 1, BB), blk, 0, stream>>>(A, wout, out);
}

// Round 12
// 834.848 us; speedup vs baseline: 4.4034x; 1.1299x over previous
//
#include <hip/hip_runtime.h>
#include <hip/hip_bf16.h>
#include <cmath>

using bf16 = __hip_bfloat16;
using bf16x8 = __attribute__((ext_vector_type(8))) short;
using f32x4v = __attribute__((ext_vector_type(4))) float;

static constexpr int BB  = 8;
static constexpr int HW  = 64;
static constexpr int NN  = HW * HW;     // 4096
static constexpr int CC  = 256;
static constexpr int CIN = 64;
static constexpr int DH  = 1024;
static constexpr int MM  = BB * NN;     // 32768

__device__ __forceinline__ bf16 f2b(float v) { return __float2bfloat16(v); }
__device__ __forceinline__ float b2f(bf16 v) { return __bfloat162float(v); }
__device__ __forceinline__ float siluf(float x) { return x / (1.f + expf(-x)); }
__device__ __forceinline__ float sigmf(float x) { return 1.f / (1.f + expf(-x)); }
__device__ __forceinline__ float geluf(float x) {
  float t = tanhf(0.7978845608028654f * (x + 0.044715f * x * x * x));
  return 0.5f * x * (1.f + t);
}

// ---------- pos table [N][C] ----------
__global__ __launch_bounds__(256) void pos_kern(float* __restrict__ pos) {
  int n = blockIdx.x, o = threadIdx.x;
  int yy = n >> 6, xx = n & 63;
  int i = o & 63, q = o >> 6;
  float omega = powf(10000.f, -(float)i / 64.f);
  float coord = (q < 2) ? (float)xx : (float)yy;
  float ang = coord * omega;
  pos[(size_t)n * CC + o] = (q & 1) ? cosf(ang) : sinf(ang);
}

// ---------- in_proj: NCHW(64ch) -> [B*N,256], tiled, + SiLU ----------
__global__ __launch_bounds__(256) void inproj_tile(const float* __restrict__ X,
                                                   const float* __restrict__ W,
                                                   float* __restrict__ H) {
  __shared__ float Xs[16][68];
  __shared__ float Ws[16][68];
  int m0 = blockIdx.x * 64, o0 = blockIdx.y * 64, b = blockIdx.z;
  int tid = threadIdx.x, tx = tid & 15, ty = tid >> 4;
  float acc[4][4] = {};
  for (int k0 = 0; k0 < CIN; k0 += 16) {
    {
      int mm = tid & 63, kk0 = tid >> 6;
#pragma unroll
      for (int i = 0; i < 4; ++i) {
        int kk = kk0 * 4 + i;
        Xs[kk][mm] = X[((size_t)(b * CIN + k0 + kk)) * NN + m0 + mm];
      }
    }
    {
      int kk = tid & 15, oo0 = tid >> 4;
#pragma unroll
      for (int i = 0; i < 4; ++i) {
        int oo = oo0 + i * 16;
        Ws[kk][oo] = W[(size_t)(o0 + oo) * CIN + k0 + kk];
      }
    }
    __syncthreads();
#pragma unroll
    for (int kk = 0; kk < 16; ++kk) {
      float xv[4], wv[4];
#pragma unroll
      for (int a = 0; a < 4; ++a) xv[a] = Xs[kk][ty * 4 + a];
#pragma unroll
      for (int c = 0; c < 4; ++c) wv[c] = Ws[kk][tx * 4 + c];
#pragma unroll
      for (int a = 0; a < 4; ++a)
#pragma unroll
        for (int c = 0; c < 4; ++c) acc[a][c] += xv[a] * wv[c];
    }
    __syncthreads();
  }
#pragma unroll
  for (int a = 0; a < 4; ++a) {
    int m = m0 + ty * 4 + a;
#pragma unroll
    for (int c = 0; c < 4; ++c) {
      int o = o0 + tx * 4 + c;
      H[((size_t)b * NN + m) * CC + o] = siluf(acc[a][c]);
    }
  }
}

// ---------- f32 tiled GEMM (out_proj only) ----------
__global__ __launch_bounds__(256) void outproj_tile(const float* __restrict__ X,
                                                    const float* __restrict__ W,
                                                    float* __restrict__ Y) {
  __shared__ float Xs[16][68];
  __shared__ float Ws[16][68];
  int n0 = blockIdx.x * 64, b = blockIdx.z;
  size_t mbase = (size_t)b * NN;
  int tid = threadIdx.x, tx = tid & 15, ty = tid >> 4;
  float acc[4][4] = {};
  for (int k0 = 0; k0 < CC; k0 += 16) {
    int kk = tid & 15, rr0 = tid >> 4;
#pragma unroll
    for (int i = 0; i < 4; ++i) {
      int rr = rr0 + i * 16;
      Xs[kk][rr] = X[(mbase + n0 + rr) * CC + k0 + kk];
      Ws[kk][rr] = (rr < CIN) ? W[(size_t)rr * CC + k0 + kk] : 0.f;
    }
    __syncthreads();
#pragma unroll
    for (int kk2 = 0; kk2 < 16; ++kk2) {
      float xv[4], wv[4];
#pragma unroll
      for (int a = 0; a < 4; ++a) xv[a] = Xs[kk2][ty * 4 + a];
#pragma unroll
      for (int c = 0; c < 4; ++c) wv[c] = Ws[kk2][tx * 4 + c];
#pragma unroll
      for (int a = 0; a < 4; ++a)
#pragma unroll
        for (int c = 0; c < 4; ++c) acc[a][c] += xv[a] * wv[c];
    }
    __syncthreads();
  }
#pragma unroll
  for (int a = 0; a < 4; ++a) {
    int n = n0 + ty * 4 + a;
#pragma unroll
    for (int c = 0; c < 4; ++c) {
      int o = tx * 4 + c;
      if (o < CIN)
        Y[(size_t)(b * CIN + o) * NN + n] = siluf(acc[a][c]);
    }
  }
}

// ---------- bf16-MFMA GEMM core, templated in/out dtype, fused epilogues ----------
enum { EPI_PLAIN = 0, EPI_BIAS = 1, EPI_QK = 2, EPI_QKT = 3, EPI_BIAST = 4,
       EPI_NUM = 5, EPI_RESID = 6 };

__device__ __forceinline__ bf16x8 pack8(const float* s) {
  union { bf16x8 v; bf16 e[8]; } u;
#pragma unroll
  for (int i = 0; i < 8; ++i) u.e[i] = __float2bfloat16(s[i]);
  return u.v;
}
__device__ __forceinline__ bf16x8 load8(const float* p) {
  float t[8];
#pragma unroll
  for (int i = 0; i < 8; ++i) t[i] = p[i];
  return pack8(t);
}
__device__ __forceinline__ bf16x8 load8(const bf16* p) { return *(const bf16x8*)p; }
__device__ __forceinline__ void storeO(float* p, float v) { *p = v; }
__device__ __forceinline__ void storeO(bf16* p, float v) { *p = f2b(v); }

// KVS: per-batch split-8 kv mode
template <int EPI, bool WPB, bool KVS, typename XT, typename YT>
__global__ __launch_bounds__(256) void gemm_mfma(const XT* __restrict__ X,
                                                 const float* __restrict__ W,
                                                 const float* __restrict__ bias,
                                                 YT* __restrict__ Y, int Kd, int Od,
                                                 const float* __restrict__ aux1,   // pose | rden
                                                 const float* __restrict__ aux2) { // psi | U1
  __shared__ bf16 As[128 * 32];
  __shared__ bf16 Bs[128 * 32];
  int m0 = blockIdx.x * 128, o0 = blockIdx.y * 128;
  int kbeg = 0, kend = Kd;
  if (KVS) {
    int b = blockIdx.z >> 3, ks = blockIdx.z & 7;
    size_t off = (size_t)b * CC * Kd;
    X += off; W += off;
    Y += (size_t)blockIdx.z * CC * CC;
    kbeg = ks * (Kd / 8); kend = kbeg + Kd / 8;
  }
  const float* Wp = WPB ? (W + (size_t)(m0 >> 12) * Kd * Od) : W;
  int t = threadIdx.x;
  int l = t & 63, w = t >> 6;
  int wm = (w >> 1) * 64, wn = (w & 1) * 64;
  int lr = l & 15, lq = l >> 4;
  f32x4v acc[4][4] = {};
  for (int k0 = kbeg; k0 < kend; k0 += 32) {
#pragma unroll
    for (int j = 0; j < 2; ++j) {
      int chunk = j * 256 + t;       // 0..511
      int row = chunk >> 2;          // 0..127
      int kc = (chunk & 3) * 8;
      *(bf16x8*)(As + row * 32 + kc) = load8(X + (size_t)(m0 + row) * Kd + k0 + kc);
      *(bf16x8*)(Bs + row * 32 + kc) = load8(Wp + (size_t)(o0 + row) * Kd + k0 + kc);
    }
    __syncthreads();
    bf16x8 af[4], bfr[4];
#pragma unroll
    for (int mt = 0; mt < 4; ++mt)
      af[mt] = *(const bf16x8*)(As + (wm + mt * 16 + lr) * 32 + lq * 8);
#pragma unroll
    for (int nt = 0; nt < 4; ++nt)
      bfr[nt] = *(const bf16x8*)(Bs + (wn + nt * 16 + lr) * 32 + lq * 8);
#pragma unroll
    for (int mt = 0; mt < 4; ++mt)
#pragma unroll
      for (int nt = 0; nt < 4; ++nt)
        acc[mt][nt] = __builtin_amdgcn_mfma_f32_16x16x32_bf16(af[mt], bfr[nt], acc[mt][nt], 0, 0, 0);
    __syncthreads();
  }
  // C/D: col = lane&15 (o), row = (lane>>4)*4 + reg (m)
#pragma unroll
  for (int nt = 0; nt < 4; ++nt) {
    int o = o0 + wn + nt * 16 + lr;
    float bv = (EPI == EPI_PLAIN || EPI == EPI_NUM) ? 0.f : bias[o];
#pragma unroll
    for (int mt = 0; mt < 4; ++mt) {
      int mb = m0 + wm + mt * 16 + lq * 4;
#pragma unroll
      for (int r = 0; r < 4; ++r) {
        int m = mb + r;
        float v = acc[mt][nt][r] + bv;
        if constexpr (EPI == EPI_PLAIN || EPI == EPI_BIAS) {
          storeO(Y + (size_t)m * Od + o, v);
        } else if constexpr (EPI == EPI_QK || EPI == EPI_QKT) {
          int n = m & (NN - 1), b = m >> 12;
          v = (v + aux1[(size_t)n * CC + o]) * aux2[(size_t)m * CC + o];
          v = fmaxf(v, 0.f);
          v = v * v;
          if constexpr (EPI == EPI_QK)
            storeO(Y + (size_t)m * Od + o, v);
          else
            storeO(Y + ((size_t)(b * CC + o)) * NN + n, v);   // phiKT[b][c][n]
        } else if constexpr (EPI == EPI_BIAST) {
          int n = m & (NN - 1), b = m >> 12;
          storeO(Y + ((size_t)(b * CC + o)) * NN + n, v);     // VT[b][d][n]
        } else if constexpr (EPI == EPI_NUM) {
          storeO(Y + (size_t)m * Od + o, v * aux1[m]);
        } else {  // EPI_RESID
          storeO(Y + (size_t)m * Od + o, v + 2.f * aux2[(size_t)m * Od + o]);
        }
      }
    }
  }
}

// ---------- kvT[b][d][c] = sum_ks kvpart[b*8+ks][d][c] ----------
__global__ __launch_bounds__(256) void kvred_kern(const float* __restrict__ part,
                                                  float* __restrict__ kvT) {
  int d = blockIdx.x, b = blockIdx.y, c = threadIdx.x;
  float s = 0.f;
#pragma unroll
  for (int ks = 0; ks < 8; ++ks)
    s += part[((size_t)(b * 8 + ks) * CC + d) * CC + c];
  kvT[((size_t)b * CC + d) * CC + c] = s;
}

// ---------- ksum[b*CC+c] = sum_n phiKT[b][c][n] ----------
__global__ __launch_bounds__(256) void csumT_kern(const float* __restrict__ PKT,
                                                  float* __restrict__ ksum) {
  int bc = blockIdx.x;
  const float* row = PKT + (size_t)bc * NN;
  int t = threadIdx.x;
  float s = 0.f;
  for (int k = t; k < NN; k += 256) s += row[k];
  __shared__ float sa[256];
  sa[t] = s; __syncthreads();
  for (int st = 128; st > 0; st >>= 1) {
    if (t < st) sa[t] += sa[t + st];
    __syncthreads();
  }
  if (t == 0) ksum[bc] = sa[0];
}

// ---------- rden[b*NN+n] = 1/(phiQ[n,:].ksum[b,:] + eps) ----------
__global__ __launch_bounds__(256) void den_kern(const float* __restrict__ PQ,
                                                const float* __restrict__ ksum,
                                                float* __restrict__ rden) {
  int n = blockIdx.x, b = blockIdx.y, c = threadIdx.x;
  size_t m = (size_t)b * NN + n;
  __shared__ float sa[256];
  sa[c] = PQ[m * CC + c] * ksum[b * CC + c];
  __syncthreads();
  for (int st = 128; st > 0; st >>= 1) {
    if (c < st) sa[c] += sa[c + st];
    __syncthreads();
  }
  if (c == 0) rden[m] = 1.f / (sa[0] + 1e-5f);
}

// ---------- DyT (optional fused residual add) ----------
template <bool RESID>
__global__ __launch_bounds__(256) void dyt_kern(const float* __restrict__ X,
                                                const float* __restrict__ R,
                                                const float* __restrict__ g,
                                                const float* __restrict__ bt,
                                                float* __restrict__ T) {
  int m = blockIdx.x, c = threadIdx.x;
  size_t idx = (size_t)m * CC + c;
  float x = X[idx];
  if constexpr (RESID) x += R[idx];
  __shared__ float sa[256], qa[256];
  sa[c] = x; qa[c] = x * x;
  __syncthreads();
  for (int st = 128; st > 0; st >>= 1) {
    if (c < st) { sa[c] += sa[c + st]; qa[c] += qa[c + st]; }
    __syncthreads();
  }
  float sum = sa[0], sq = qa[0];
  float mu = sum * (1.f / 256.f);
  float var = (sq - 256.f * mu * mu) * (1.f / 255.f);
  float sd = sqrtf(fmaxf(var, 0.f)) + 1e-5f;
  T[idx] = tanhf(g[c] * (x - mu) / sd + bt[c]);
}

// ---------- pool[b][c] = sum_n T[b,n,c] ----------
__global__ __launch_bounds__(256) void pool_kern(const float* __restrict__ T,
                                                 float* __restrict__ pool) {
  int b = blockIdx.x, c = blockIdx.y, t = threadIdx.x;
  float s = 0.f;
  for (int k = 0; k < 16; ++k)
    s += T[((size_t)b * NN + t + 256 * k) * CC + c];
  __shared__ float sa[256];
  sa[t] = s; __syncthreads();
  for (int st = 128; st > 0; st >>= 1) {
    if (t < st) sa[t] += sa[t + st];
    __syncthreads();
  }
  if (t == 0) pool[b * CC + c] = sa[0];
}

// ---------- gate[b][o] = sigmoid(m_w . pool[b]/4096 + m_b) ----------
__global__ __launch_bounds__(256) void gate_kern(const float* __restrict__ pool,
                                                 const float* __restrict__ w,
                                                 const float* __restrict__ bias,
                                                 float* __restrict__ gate) {
  int b = blockIdx.x, o = threadIdx.x;
  __shared__ float p[CC];
  p[o] = pool[b * CC + o] * (1.f / 4096.f);
  __syncthreads();
  float s = bias[o];
  for (int c = 0; c < CC; ++c) s += p[c] * w[o * CC + c];
  gate[b * CC + o] = sigmf(s);
}

// ---------- O = T * gate[b][c] ----------
__global__ __launch_bounds__(256) void scale_kern(const float* __restrict__ T,
                                                  const float* __restrict__ gate,
                                                  float* __restrict__ O_) {
  size_t i = (size_t)blockIdx.x * 256 + threadIdx.x;
  int b = (int)(i >> 20);
  int c = (int)(i & (CC - 1));
  O_[i] = T[i] * gate[b * CC + c];
}

// ---------- depthwise 3x3 + sigmoid, f32 (psi) ----------
__global__ __launch_bounds__(256) void dwconv_psi(const float* __restrict__ X,
                                                  const float* __restrict__ w,
                                                  const float* __restrict__ bias,
                                                  float* __restrict__ Y) {
  int b = blockIdx.z;
  const float* Xb = X + (size_t)b * NN * CC;
  float* Yb       = Y + (size_t)b * NN * CC;
  int c = blockIdx.x * 64 + (threadIdx.x & 63);
  int yy = blockIdx.y;
  int xq = threadIdx.x >> 6;
  float wr[9];
#pragma unroll
  for (int j = 0; j < 9; ++j) wr[j] = w[c * 9 + j];
  float bb = bias[c];
  for (int x0 = xq; x0 < HW; x0 += 4) {
    float acc = bb;
#pragma unroll
    for (int ky = 0; ky < 3; ++ky) {
      int y2 = yy + ky - 1;
      if (y2 < 0 || y2 >= HW) continue;
#pragma unroll
      for (int kx = 0; kx < 3; ++kx) {
        int x2 = x0 + kx - 1;
        if (x2 < 0 || x2 >= HW) continue;
        acc += Xb[((size_t)y2 * HW + x2) * CC + c] * wr[ky * 3 + kx];
      }
    }
    Yb[((size_t)yy * HW + x0) * CC + c] = sigmf(acc);
  }
}

// ---------- depthwise 3x3 + gelu, bf16 in/out, channel pairs ----------
__global__ __launch_bounds__(256) void dwconv1024_bf16(const bf16* __restrict__ X,
                                                       const float* __restrict__ w,
                                                       const float* __restrict__ bias,
                                                       bf16* __restrict__ Y) {
  int b = blockIdx.z;
  const __hip_bfloat162* Xb = (const __hip_bfloat162*)(X + (size_t)b * NN * DH);
  __hip_bfloat162* Yb       = (__hip_bfloat162*)(Y + (size_t)b * NN * DH);
  int p = blockIdx.x * 64 + (threadIdx.x & 63);   // channel pair 0..511
  int yy = blockIdx.y;
  int xq = threadIdx.x >> 6;
  int c0 = p * 2;
  float wr0[9], wr1[9];
#pragma unroll
  for (int j = 0; j < 9; ++j) { wr0[j] = w[c0 * 9 + j]; wr1[j] = w[(c0 + 1) * 9 + j]; }
  float b0 = bias[c0], b1 = bias[c0 + 1];
  for (int x0 = xq; x0 < HW; x0 += 4) {
    float a0 = b0, a1 = b1;
#pragma unroll
    for (int ky = 0; ky < 3; ++ky) {
      int y2 = yy + ky - 1;
      if (y2 < 0 || y2 >= HW) continue;
#pragma unroll
      for (int kx = 0; kx < 3; ++kx) {
        int x2 = x0 + kx - 1;
        if (x2 < 0 || x2 >= HW) continue;
        __hip_bfloat162 v = Xb[((size_t)y2 * HW + x2) * 512 + p];
        a0 += b2f(v.x) * wr0[ky * 3 + kx];
        a1 += b2f(v.y) * wr1[ky * 3 + kx];
      }
    }
    __hip_bfloat162 r;
    r.x = f2b(geluf(a0));
    r.y = f2b(geluf(a1));
    Yb[((size_t)yy * HW + x0) * 512 + p] = r;
  }
}

extern "C" void kernel_launch(void* const* d_in, const int* in_sizes, int n_in,
                              void* d_out, int out_size, void* d_ws, size_t ws_size,
                              hipStream_t stream) {
  (void)in_sizes; (void)n_in; (void)out_size; (void)ws_size;
  const float* x       = (const float*)d_in[0];
  const float* in_proj = (const float*)d_in[1];
  const float* wq_w = (const float*)d_in[2];   const float* wq_b = (const float*)d_in[3];
  const float* wk_w = (const float*)d_in[4];   const float* wk_b = (const float*)d_in[5];
  const float* wv_w = (const float*)d_in[6];   const float* wv_b = (const float*)d_in[7];
  const float* wo_w = (const float*)d_in[8];   const float* wo_b = (const float*)d_in[9];
  const float* psi_w = (const float*)d_in[10]; const float* psi_b = (const float*)d_in[11];
  const float* dyt_g = (const float*)d_in[12]; const float* dyt_b = (const float*)d_in[13];
  const float* m1_w = (const float*)d_in[14];  const float* m1_b = (const float*)d_in[15];
  const float* m2_w = (const float*)d_in[16];  const float* m2_b = (const float*)d_in[17];
  const float* we_w = (const float*)d_in[18];  const float* we_b = (const float*)d_in[19];
  const float* dw_w = (const float*)d_in[20];  const float* dw_b = (const float*)d_in[21];
  const float* wp_w = (const float*)d_in[22];  const float* wp_b = (const float*)d_in[23];
  const float* wout = (const float*)d_in[24];
  float* out = (float*)d_out;

  char* ws = (char*)d_ws;
  const size_t MB = 1u << 20;
  float* H     = (float*)(ws);               // h -> U1
  float* A     = (float*)(ws + 32 * MB);     // a -> U2 -> Y
  float* psiB  = (float*)(ws + 64 * MB);     // psi -> num ; later e1 bf16 / T2
  float* phiQ  = (float*)(ws + 96 * MB);
  float* phiKT = (float*)(ws + 128 * MB);    // [B][C][N]; later e2 bf16 / T1
  float* VT    = (float*)(ws + 160 * MB);    // [B][C][N]
  float* numb  = psiB;
  bf16*  e1    = (bf16*)psiB;                // 32 MiB (4 batches x 4096 x 1024 bf16)
  bf16*  e2    = (bf16*)phiKT;
  float* T1    = phiKT;                      // dyt1 out (before EDFFN)
  float* T2    = psiB;                       // dyt2 out (after EDFFN)
  float* kvpart = (float*)(ws + 192 * MB);   // 16 MiB [64][C][C]
  float* kvT    = (float*)(ws + 208 * MB);   // 2 MiB [B][C][C]
  float* pose   = (float*)(ws + 210 * MB);   // 4 MiB
  char*  small  = ws + 214 * MB;
  float* ksum  = (float*)(small);
  float* rden  = (float*)(small + 64 * 1024);    // 128 KiB
  float* pool1 = (float*)(small + 256 * 1024);
  float* pool2 = (float*)(small + 272 * 1024);
  float* gate1 = (float*)(small + 288 * 1024);
  float* gate2 = (float*)(small + 304 * 1024);

  dim3 blk(256);
  const size_t NC = (size_t)NN * CC;

  pos_kern<<<dim3(NN), blk, 0, stream>>>(pose);
  inproj_tile<<<dim3(64, 4, BB), blk, 0, stream>>>(x, in_proj, H);

  // ---- attention (all MFMA, f32 storage) ----
  dwconv_psi<<<dim3(4, 64, BB), blk, 0, stream>>>(H, psi_w, psi_b, psiB);
  gemm_mfma<EPI_QK, false, false, float, float><<<dim3(256, 2), blk, 0, stream>>>(H, wq_w, wq_b, phiQ, CC, CC, pose, psiB);
  gemm_mfma<EPI_QKT, false, false, float, float><<<dim3(256, 2), blk, 0, stream>>>(H, wk_w, wk_b, phiKT, CC, CC, pose, psiB);
  gemm_mfma<EPI_BIAST, false, false, float, float><<<dim3(256, 2), blk, 0, stream>>>(H, wv_w, wv_b, VT, CC, CC, nullptr, nullptr);
  gemm_mfma<EPI_PLAIN, false, true, float, float><<<dim3(2, 2, 64), blk, 0, stream>>>(VT, phiKT, nullptr, kvpart, NN, CC, nullptr, nullptr);
  kvred_kern<<<dim3(CC, BB), blk, 0, stream>>>(kvpart, kvT);
  csumT_kern<<<dim3(BB * CC), blk, 0, stream>>>(phiKT, ksum);
  den_kern<<<dim3(NN, BB), blk, 0, stream>>>(phiQ, ksum, rden);
  gemm_mfma<EPI_NUM, true, false, float, float><<<dim3(256, 2), blk, 0, stream>>>(phiQ, kvT, nullptr, numb, CC, CC, rden, nullptr);
  gemm_mfma<EPI_BIAS, false, false, float, float><<<dim3(256, 2), blk, 0, stream>>>(numb, wo_w, wo_b, A, CC, CC, nullptr, nullptr);

  // ---- U1 = mona1(dyt(h + a)) ----
  dyt_kern<true><<<dim3(MM), blk, 0, stream>>>(H, A, dyt_g, dyt_b, T1);
  pool_kern<<<dim3(BB, CC), blk, 0, stream>>>(T1, pool1);
  gate_kern<<<dim3(BB), blk, 0, stream>>>(pool1, m1_w, m1_b, gate1);
  scale_kern<<<dim3(MM), blk, 0, stream>>>(T1, gate1, H);   // H = U1

  // ---- EDFFN, 2 passes x 4 batches; e1/e2 in bf16 ----
  for (int p = 0; p < 2; ++p) {
    const float* u1p = H + (size_t)(4 * p) * NC;
    float* u2p       = A + (size_t)(4 * p) * NC;
    gemm_mfma<EPI_BIAS, false, false, float, bf16><<<dim3(128, 8), blk, 0, stream>>>(u1p, we_w, we_b, e1, CC, DH, nullptr, nullptr);
    dwconv1024_bf16<<<dim3(8, 64, 4), blk, 0, stream>>>(e1, dw_w, dw_b, e2);
    gemm_mfma<EPI_RESID, false, false, bf16, float><<<dim3(128, 2), blk, 0, stream>>>(e2, wp_w, wp_b, u2p, DH, CC, nullptr, u1p);
  }

  // ---- Y = mona2(dyt(U2)) ----
  dyt_kern<false><<<dim3(MM), blk, 0, stream>>>(A, nullptr, dyt_g, dyt_b, T2);
  pool_kern<<<dim3(BB, CC), blk, 0, stream>>>(T2, pool2);
  gate_kern<<<dim3(BB), blk, 0, stream>>>(pool2, m2_w, m2_b, gate2);
  scale_kern<<<dim3(MM), blk, 0, stream>>>(T2, gate2, A);   // A = Y

  // ---- out_proj + SiLU, transposed write ----
  outproj_tile<<<dim3(64, 1, BB), blk, 0, stream>>>(A, wout, out);
}

// Round 13
// 785.285 us; speedup vs baseline: 4.6813x; 1.0631x over previous
//
#include <hip/hip_runtime.h>
#include <hip/hip_bf16.h>
#include <cmath>

using bf16 = __hip_bfloat16;
using bf16x8 = __attribute__((ext_vector_type(8))) short;
using f32x4v = __attribute__((ext_vector_type(4))) float;

static constexpr int BB  = 8;
static constexpr int HW  = 64;
static constexpr int NN  = HW * HW;     // 4096
static constexpr int CC  = 256;
static constexpr int CIN = 64;
static constexpr int DH  = 1024;
static constexpr int MM  = BB * NN;     // 32768

__device__ __forceinline__ bf16 f2b(float v) { return __float2bfloat16(v); }
__device__ __forceinline__ float b2f(bf16 v) { return __bfloat162float(v); }
__device__ __forceinline__ float tf(float v) { return v; }
__device__ __forceinline__ float tf(bf16 v)  { return b2f(v); }
__device__ __forceinline__ float siluf(float x) { return x / (1.f + expf(-x)); }
__device__ __forceinline__ float sigmf(float x) { return 1.f / (1.f + expf(-x)); }
__device__ __forceinline__ float geluf(float x) {
  float t = tanhf(0.7978845608028654f * (x + 0.044715f * x * x * x));
  return 0.5f * x * (1.f + t);
}

// ---------- pos table [N][C] ----------
__global__ __launch_bounds__(256) void pos_kern(float* __restrict__ pos) {
  int n = blockIdx.x, o = threadIdx.x;
  int yy = n >> 6, xx = n & 63;
  int i = o & 63, q = o >> 6;
  float omega = powf(10000.f, -(float)i / 64.f);
  float coord = (q < 2) ? (float)xx : (float)yy;
  float ang = coord * omega;
  pos[(size_t)n * CC + o] = (q & 1) ? cosf(ang) : sinf(ang);
}

// ---------- in_proj: NCHW(64ch) -> [B*N,256], tiled, + SiLU ----------
__global__ __launch_bounds__(256) void inproj_tile(const float* __restrict__ X,
                                                   const float* __restrict__ W,
                                                   float* __restrict__ H) {
  __shared__ float Xs[16][68];
  __shared__ float Ws[16][68];
  int m0 = blockIdx.x * 64, o0 = blockIdx.y * 64, b = blockIdx.z;
  int tid = threadIdx.x, tx = tid & 15, ty = tid >> 4;
  float acc[4][4] = {};
  for (int k0 = 0; k0 < CIN; k0 += 16) {
    {
      int mm = tid & 63, kk0 = tid >> 6;
#pragma unroll
      for (int i = 0; i < 4; ++i) {
        int kk = kk0 * 4 + i;
        Xs[kk][mm] = X[((size_t)(b * CIN + k0 + kk)) * NN + m0 + mm];
      }
    }
    {
      int kk = tid & 15, oo0 = tid >> 4;
#pragma unroll
      for (int i = 0; i < 4; ++i) {
        int oo = oo0 + i * 16;
        Ws[kk][oo] = W[(size_t)(o0 + oo) * CIN + k0 + kk];
      }
    }
    __syncthreads();
#pragma unroll
    for (int kk = 0; kk < 16; ++kk) {
      float xv[4], wv[4];
#pragma unroll
      for (int a = 0; a < 4; ++a) xv[a] = Xs[kk][ty * 4 + a];
#pragma unroll
      for (int c = 0; c < 4; ++c) wv[c] = Ws[kk][tx * 4 + c];
#pragma unroll
      for (int a = 0; a < 4; ++a)
#pragma unroll
        for (int c = 0; c < 4; ++c) acc[a][c] += xv[a] * wv[c];
    }
    __syncthreads();
  }
#pragma unroll
  for (int a = 0; a < 4; ++a) {
    int m = m0 + ty * 4 + a;
#pragma unroll
    for (int c = 0; c < 4; ++c) {
      int o = o0 + tx * 4 + c;
      H[((size_t)b * NN + m) * CC + o] = siluf(acc[a][c]);
    }
  }
}

// ---------- f32 tiled GEMM (out_proj only) ----------
__global__ __launch_bounds__(256) void outproj_tile(const float* __restrict__ X,
                                                    const float* __restrict__ W,
                                                    float* __restrict__ Y) {
  __shared__ float Xs[16][68];
  __shared__ float Ws[16][68];
  int n0 = blockIdx.x * 64, b = blockIdx.z;
  size_t mbase = (size_t)b * NN;
  int tid = threadIdx.x, tx = tid & 15, ty = tid >> 4;
  float acc[4][4] = {};
  for (int k0 = 0; k0 < CC; k0 += 16) {
    int kk = tid & 15, rr0 = tid >> 4;
#pragma unroll
    for (int i = 0; i < 4; ++i) {
      int rr = rr0 + i * 16;
      Xs[kk][rr] = X[(mbase + n0 + rr) * CC + k0 + kk];
      Ws[kk][rr] = (rr < CIN) ? W[(size_t)rr * CC + k0 + kk] : 0.f;
    }
    __syncthreads();
#pragma unroll
    for (int kk2 = 0; kk2 < 16; ++kk2) {
      float xv[4], wv[4];
#pragma unroll
      for (int a = 0; a < 4; ++a) xv[a] = Xs[kk2][ty * 4 + a];
#pragma unroll
      for (int c = 0; c < 4; ++c) wv[c] = Ws[kk2][tx * 4 + c];
#pragma unroll
      for (int a = 0; a < 4; ++a)
#pragma unroll
        for (int c = 0; c < 4; ++c) acc[a][c] += xv[a] * wv[c];
    }
    __syncthreads();
  }
#pragma unroll
  for (int a = 0; a < 4; ++a) {
    int n = n0 + ty * 4 + a;
#pragma unroll
    for (int c = 0; c < 4; ++c) {
      int o = tx * 4 + c;
      if (o < CIN)
        Y[(size_t)(b * CIN + o) * NN + n] = siluf(acc[a][c]);
    }
  }
}

// ---------- bf16-MFMA GEMM core, templated dtypes, fused epilogues ----------
enum { EPI_PLAIN = 0, EPI_BIAS = 1, EPI_QK = 2, EPI_NUM = 3, EPI_RESID = 4 };

__device__ __forceinline__ bf16x8 pack8(const float* s) {
  union { bf16x8 v; bf16 e[8]; } u;
#pragma unroll
  for (int i = 0; i < 8; ++i) u.e[i] = __float2bfloat16(s[i]);
  return u.v;
}
__device__ __forceinline__ bf16x8 load8(const float* p) {
  float t[8];
#pragma unroll
  for (int i = 0; i < 8; ++i) t[i] = p[i];
  return pack8(t);
}
__device__ __forceinline__ bf16x8 load8(const bf16* p) { return *(const bf16x8*)p; }
__device__ __forceinline__ void storeO(float* p, float v) { *p = v; }
__device__ __forceinline__ void storeO(bf16* p, float v) { *p = f2b(v); }

// KVS: per-batch split-8 kv mode (z = b*8+ks)
template <int EPI, bool WPB, bool KVS, typename XT, typename WT, typename YT, typename A2T>
__global__ __launch_bounds__(256) void gemm_mfma(const XT* __restrict__ X,
                                                 const WT* __restrict__ W,
                                                 const float* __restrict__ bias,
                                                 YT* __restrict__ Y, int Kd, int Od,
                                                 const float* __restrict__ aux1,   // pose | rden
                                                 const A2T* __restrict__ aux2) {   // psi | U1
  __shared__ __align__(16) bf16 As[128 * 32];
  __shared__ __align__(16) bf16 Bs[128 * 32];
  int m0 = blockIdx.x * 128, o0 = blockIdx.y * 128;
  int kbeg = 0, kend = Kd;
  if (KVS) {
    int b = blockIdx.z >> 3, ks = blockIdx.z & 7;
    size_t off = (size_t)b * CC * Kd;
    X += off; W += off;
    Y += (size_t)blockIdx.z * CC * CC;
    kbeg = ks * (Kd / 8); kend = kbeg + Kd / 8;
  }
  const WT* Wp = WPB ? (W + (size_t)(m0 >> 12) * Kd * Od) : W;
  int t = threadIdx.x;
  int l = t & 63, w = t >> 6;
  int wm = (w >> 1) * 64, wn = (w & 1) * 64;
  int lr = l & 15, lq = l >> 4;
  f32x4v acc[4][4] = {};
  for (int k0 = kbeg; k0 < kend; k0 += 32) {
#pragma unroll
    for (int j = 0; j < 2; ++j) {
      int chunk = j * 256 + t;
      int row = chunk >> 2;
      int kc = (chunk & 3) * 8;
      *(bf16x8*)(As + row * 32 + kc) = load8(X + (size_t)(m0 + row) * Kd + k0 + kc);
      *(bf16x8*)(Bs + row * 32 + kc) = load8(Wp + (size_t)(o0 + row) * Kd + k0 + kc);
    }
    __syncthreads();
    bf16x8 af[4], bfr[4];
#pragma unroll
    for (int mt = 0; mt < 4; ++mt)
      af[mt] = *(const bf16x8*)(As + (wm + mt * 16 + lr) * 32 + lq * 8);
#pragma unroll
    for (int nt = 0; nt < 4; ++nt)
      bfr[nt] = *(const bf16x8*)(Bs + (wn + nt * 16 + lr) * 32 + lq * 8);
#pragma unroll
    for (int mt = 0; mt < 4; ++mt)
#pragma unroll
      for (int nt = 0; nt < 4; ++nt)
        acc[mt][nt] = __builtin_amdgcn_mfma_f32_16x16x32_bf16(af[mt], bfr[nt], acc[mt][nt], 0, 0, 0);
    __syncthreads();
  }
  // C/D: col = lane&15 (o), row = (lane>>4)*4 + reg (m)
#pragma unroll
  for (int nt = 0; nt < 4; ++nt) {
    int o = o0 + wn + nt * 16 + lr;
    float bv = (EPI == EPI_PLAIN || EPI == EPI_NUM) ? 0.f : bias[o];
#pragma unroll
    for (int mt = 0; mt < 4; ++mt) {
      int mb = m0 + wm + mt * 16 + lq * 4;
#pragma unroll
      for (int r = 0; r < 4; ++r) {
        int m = mb + r;
        float v = acc[mt][nt][r] + bv;
        if constexpr (EPI == EPI_PLAIN || EPI == EPI_BIAS) {
          storeO(Y + (size_t)m * Od + o, v);
        } else if constexpr (EPI == EPI_QK) {
          int n = m & (NN - 1);
          v = (v + aux1[(size_t)n * CC + o]) * tf(aux2[(size_t)m * CC + o]);
          v = fmaxf(v, 0.f);
          storeO(Y + (size_t)m * Od + o, v * v);
        } else if constexpr (EPI == EPI_NUM) {
          storeO(Y + (size_t)m * Od + o, v * aux1[m]);
        } else {  // EPI_RESID
          storeO(Y + (size_t)m * Od + o, v + 2.f * tf(aux2[(size_t)m * Od + o]));
        }
      }
    }
  }
}

// ---------- MFMA GEMM with transposed coalesced bf16 output: Y[b][o][n] ----------
// QKMATH: apply psi*(v+bias+pos), relu^2 (K). else bias only (V).
template <bool QKMATH>
__global__ __launch_bounds__(256) void gemm_mfma_T(const float* __restrict__ X,
                                                   const float* __restrict__ W,
                                                   const float* __restrict__ bias,
                                                   bf16* __restrict__ Y,
                                                   const float* __restrict__ pose,
                                                   const bf16* __restrict__ psi) {
  __shared__ __align__(16) bf16 As[128 * 32];
  __shared__ __align__(16) bf16 Bs[128 * 32];
  __shared__ __align__(16) bf16 Ts[128 * 136];
  int m0 = blockIdx.x * 128, o0 = blockIdx.y * 128;
  int t = threadIdx.x;
  int l = t & 63, w = t >> 6;
  int wm = (w >> 1) * 64, wn = (w & 1) * 64;
  int lr = l & 15, lq = l >> 4;
  f32x4v acc[4][4] = {};
  for (int k0 = 0; k0 < CC; k0 += 32) {
#pragma unroll
    for (int j = 0; j < 2; ++j) {
      int chunk = j * 256 + t;
      int row = chunk >> 2;
      int kc = (chunk & 3) * 8;
      *(bf16x8*)(As + row * 32 + kc) = load8(X + (size_t)(m0 + row) * CC + k0 + kc);
      *(bf16x8*)(Bs + row * 32 + kc) = load8(W + (size_t)(o0 + row) * CC + k0 + kc);
    }
    __syncthreads();
    bf16x8 af[4], bfr[4];
#pragma unroll
    for (int mt = 0; mt < 4; ++mt)
      af[mt] = *(const bf16x8*)(As + (wm + mt * 16 + lr) * 32 + lq * 8);
#pragma unroll
    for (int nt = 0; nt < 4; ++nt)
      bfr[nt] = *(const bf16x8*)(Bs + (wn + nt * 16 + lr) * 32 + lq * 8);
#pragma unroll
    for (int mt = 0; mt < 4; ++mt)
#pragma unroll
      for (int nt = 0; nt < 4; ++nt)
        acc[mt][nt] = __builtin_amdgcn_mfma_f32_16x16x32_bf16(af[mt], bfr[nt], acc[mt][nt], 0, 0, 0);
    __syncthreads();
  }
  // epilogue -> LDS transpose tile
#pragma unroll
  for (int nt = 0; nt < 4; ++nt) {
    int ol = wn + nt * 16 + lr;
    int o = o0 + ol;
    float bv = bias[o];
#pragma unroll
    for (int mt = 0; mt < 4; ++mt) {
      int mlb = wm + mt * 16 + lq * 4;
#pragma unroll
      for (int r = 0; r < 4; ++r) {
        int ml = mlb + r;
        int m = m0 + ml;
        float v = acc[mt][nt][r] + bv;
        if constexpr (QKMATH) {
          int n = m & (NN - 1);
          v = (v + pose[(size_t)n * CC + o]) * b2f(psi[(size_t)m * CC + o]);
          v = fmaxf(v, 0.f);
          v = v * v;
        }
        Ts[ol * 136 + ml] = f2b(v);
      }
    }
  }
  __syncthreads();
  // coalesced writeout: Y[(b*CC + o)*NN + n]
  int b = m0 >> 12, n0 = m0 & (NN - 1);
  int ol = t >> 1, half = t & 1;
  const bf16* src = Ts + ol * 136 + half * 64;
  bf16* dst = Y + ((size_t)(b * CC + o0 + ol)) * NN + n0 + half * 64;
#pragma unroll
  for (int j = 0; j < 8; ++j)
    *(bf16x8*)(dst + j * 8) = *(const bf16x8*)(src + j * 8);
}

// ---------- kvT[b][d][c] = sum_ks kvpart[b*8+ks][d][c] ----------
__global__ __launch_bounds__(256) void kvred_kern(const float* __restrict__ part,
                                                  float* __restrict__ kvT) {
  int d = blockIdx.x, b = blockIdx.y, c = threadIdx.x;
  float s = 0.f;
#pragma unroll
  for (int ks = 0; ks < 8; ++ks)
    s += part[((size_t)(b * 8 + ks) * CC + d) * CC + c];
  kvT[((size_t)b * CC + d) * CC + c] = s;
}

// ---------- ksum[b*CC+c] = sum_n phiKT[b][c][n]  (bf16 rows) ----------
__global__ __launch_bounds__(256) void csumT_kern(const bf16* __restrict__ PKT,
                                                  float* __restrict__ ksum) {
  int bc = blockIdx.x;
  const bf16* row = PKT + (size_t)bc * NN;
  int t = threadIdx.x;
  float s = 0.f;
  for (int k = t; k < NN; k += 256) s += b2f(row[k]);
  __shared__ float sa[256];
  sa[t] = s; __syncthreads();
  for (int st = 128; st > 0; st >>= 1) {
    if (t < st) sa[t] += sa[t + st];
    __syncthreads();
  }
  if (t == 0) ksum[bc] = sa[0];
}

// ---------- rden[b*NN+n] = 1/(phiQ[n,:].ksum[b,:] + eps), phiQ bf16 ----------
__global__ __launch_bounds__(256) void den_kern(const bf16* __restrict__ PQ,
                                                const float* __restrict__ ksum,
                                                float* __restrict__ rden) {
  int n = blockIdx.x, b = blockIdx.y, c = threadIdx.x;
  size_t m = (size_t)b * NN + n;
  __shared__ float sa[256];
  sa[c] = b2f(PQ[m * CC + c]) * ksum[b * CC + c];
  __syncthreads();
  for (int st = 128; st > 0; st >>= 1) {
    if (c < st) sa[c] += sa[c + st];
    __syncthreads();
  }
  if (c == 0) rden[m] = 1.f / (sa[0] + 1e-5f);
}

// ---------- DyT (optional fused residual add) ----------
template <bool RESID>
__global__ __launch_bounds__(256) void dyt_kern(const float* __restrict__ X,
                                                const float* __restrict__ R,
                                                const float* __restrict__ g,
                                                const float* __restrict__ bt,
                                                float* __restrict__ T) {
  int m = blockIdx.x, c = threadIdx.x;
  size_t idx = (size_t)m * CC + c;
  float x = X[idx];
  if constexpr (RESID) x += R[idx];
  __shared__ float sa[256], qa[256];
  sa[c] = x; qa[c] = x * x;
  __syncthreads();
  for (int st = 128; st > 0; st >>= 1) {
    if (c < st) { sa[c] += sa[c + st]; qa[c] += qa[c + st]; }
    __syncthreads();
  }
  float sum = sa[0], sq = qa[0];
  float mu = sum * (1.f / 256.f);
  float var = (sq - 256.f * mu * mu) * (1.f / 255.f);
  float sd = sqrtf(fmaxf(var, 0.f)) + 1e-5f;
  T[idx] = tanhf(g[c] * (x - mu) / sd + bt[c]);
}

// ---------- pool[b][c] = sum_n T[b,n,c] ----------
__global__ __launch_bounds__(256) void pool_kern(const float* __restrict__ T,
                                                 float* __restrict__ pool) {
  int b = blockIdx.x, c = blockIdx.y, t = threadIdx.x;
  float s = 0.f;
  for (int k = 0; k < 16; ++k)
    s += T[((size_t)b * NN + t + 256 * k) * CC + c];
  __shared__ float sa[256];
  sa[t] = s; __syncthreads();
  for (int st = 128; st > 0; st >>= 1) {
    if (t < st) sa[t] += sa[t + st];
    __syncthreads();
  }
  if (t == 0) pool[b * CC + c] = sa[0];
}

// ---------- gate[b][o] = sigmoid(m_w . pool[b]/4096 + m_b) ----------
__global__ __launch_bounds__(256) void gate_kern(const float* __restrict__ pool,
                                                 const float* __restrict__ w,
                                                 const float* __restrict__ bias,
                                                 float* __restrict__ gate) {
  int b = blockIdx.x, o = threadIdx.x;
  __shared__ float p[CC];
  p[o] = pool[b * CC + o] * (1.f / 4096.f);
  __syncthreads();
  float s = bias[o];
  for (int c = 0; c < CC; ++c) s += p[c] * w[o * CC + c];
  gate[b * CC + o] = sigmf(s);
}

// ---------- O = T * gate[b][c] ----------
__global__ __launch_bounds__(256) void scale_kern(const float* __restrict__ T,
                                                  const float* __restrict__ gate,
                                                  float* __restrict__ O_) {
  size_t i = (size_t)blockIdx.x * 256 + threadIdx.x;
  int b = (int)(i >> 20);
  int c = (int)(i & (CC - 1));
  O_[i] = T[i] * gate[b * CC + c];
}

// ---------- depthwise 3x3 + sigmoid, f32 in -> bf16 out (psi) ----------
__global__ __launch_bounds__(256) void dwconv_psi(const float* __restrict__ X,
                                                  const float* __restrict__ w,
                                                  const float* __restrict__ bias,
                                                  bf16* __restrict__ Y) {
  int b = blockIdx.z;
  const float* Xb = X + (size_t)b * NN * CC;
  bf16* Yb       = Y + (size_t)b * NN * CC;
  int c = blockIdx.x * 64 + (threadIdx.x & 63);
  int yy = blockIdx.y;
  int xq = threadIdx.x >> 6;
  float wr[9];
#pragma unroll
  for (int j = 0; j < 9; ++j) wr[j] = w[c * 9 + j];
  float bb = bias[c];
  for (int x0 = xq; x0 < HW; x0 += 4) {
    float acc = bb;
#pragma unroll
    for (int ky = 0; ky < 3; ++ky) {
      int y2 = yy + ky - 1;
      if (y2 < 0 || y2 >= HW) continue;
#pragma unroll
      for (int kx = 0; kx < 3; ++kx) {
        int x2 = x0 + kx - 1;
        if (x2 < 0 || x2 >= HW) continue;
        acc += Xb[((size_t)y2 * HW + x2) * CC + c] * wr[ky * 3 + kx];
      }
    }
    Yb[((size_t)yy * HW + x0) * CC + c] = f2b(sigmf(acc));
  }
}

// ---------- depthwise 3x3 + gelu, bf16 in/out, channel pairs ----------
__global__ __launch_bounds__(256) void dwconv1024_bf16(const bf16* __restrict__ X,
                                                       const float* __restrict__ w,
                                                       const float* __restrict__ bias,
                                                       bf16* __restrict__ Y) {
  int b = blockIdx.z;
  const __hip_bfloat162* Xb = (const __hip_bfloat162*)(X + (size_t)b * NN * DH);
  __hip_bfloat162* Yb       = (__hip_bfloat162*)(Y + (size_t)b * NN * DH);
  int p = blockIdx.x * 64 + (threadIdx.x & 63);
  int yy = blockIdx.y;
  int xq = threadIdx.x >> 6;
  int c0 = p * 2;
  float wr0[9], wr1[9];
#pragma unroll
  for (int j = 0; j < 9; ++j) { wr0[j] = w[c0 * 9 + j]; wr1[j] = w[(c0 + 1) * 9 + j]; }
  float b0 = bias[c0], b1 = bias[c0 + 1];
  for (int x0 = xq; x0 < HW; x0 += 4) {
    float a0 = b0, a1 = b1;
#pragma unroll
    for (int ky = 0; ky < 3; ++ky) {
      int y2 = yy + ky - 1;
      if (y2 < 0 || y2 >= HW) continue;
#pragma unroll
      for (int kx = 0; kx < 3; ++kx) {
        int x2 = x0 + kx - 1;
        if (x2 < 0 || x2 >= HW) continue;
        __hip_bfloat162 v = Xb[((size_t)y2 * HW + x2) * 512 + p];
        a0 += b2f(v.x) * wr0[ky * 3 + kx];
        a1 += b2f(v.y) * wr1[ky * 3 + kx];
      }
    }
    __hip_bfloat162 r;
    r.x = f2b(geluf(a0));
    r.y = f2b(geluf(a1));
    Yb[((size_t)yy * HW + x0) * 512 + p] = r;
  }
}

extern "C" void kernel_launch(void* const* d_in, const int* in_sizes, int n_in,
                              void* d_out, int out_size, void* d_ws, size_t ws_size,
                              hipStream_t stream) {
  (void)in_sizes; (void)n_in; (void)out_size; (void)ws_size;
  const float* x       = (const float*)d_in[0];
  const float* in_proj = (const float*)d_in[1];
  const float* wq_w = (const float*)d_in[2];   const float* wq_b = (const float*)d_in[3];
  const float* wk_w = (const float*)d_in[4];   const float* wk_b = (const float*)d_in[5];
  const float* wv_w = (const float*)d_in[6];   const float* wv_b = (const float*)d_in[7];
  const float* wo_w = (const float*)d_in[8];   const float* wo_b = (const float*)d_in[9];
  const float* psi_w = (const float*)d_in[10]; const float* psi_b = (const float*)d_in[11];
  const float* dyt_g = (const float*)d_in[12]; const float* dyt_b = (const float*)d_in[13];
  const float* m1_w = (const float*)d_in[14];  const float* m1_b = (const float*)d_in[15];
  const float* m2_w = (const float*)d_in[16];  const float* m2_b = (const float*)d_in[17];
  const float* we_w = (const float*)d_in[18];  const float* we_b = (const float*)d_in[19];
  const float* dw_w = (const float*)d_in[20];  const float* dw_b = (const float*)d_in[21];
  const float* wp_w = (const float*)d_in[22];  const float* wp_b = (const float*)d_in[23];
  const float* wout = (const float*)d_in[24];
  float* out = (float*)d_out;

  char* ws = (char*)d_ws;
  const size_t MB = 1u << 20;
  float* H     = (float*)(ws);               // h -> U1               32 MiB
  float* A     = (float*)(ws + 32 * MB);     // a -> U2 -> Y          32 MiB
  bf16*  psiB  = (bf16*)(ws + 64 * MB);      // 16 MiB
  bf16*  numb  = (bf16*)(ws + 80 * MB);      // 16 MiB
  bf16*  phiQ  = (bf16*)(ws + 96 * MB);      // 16 MiB
  bf16*  phiKT = (bf16*)(ws + 128 * MB);     // 16 MiB [B][C][N]
  bf16*  VT    = (bf16*)(ws + 144 * MB);     // 16 MiB [B][C][N]
  bf16*  e1    = (bf16*)(ws + 64 * MB);      // 32 MiB (overlays psiB+numb, EDFFN)
  bf16*  e2    = (bf16*)(ws + 128 * MB);     // 32 MiB (overlays phiKT+VT, EDFFN)
  float* T1    = (float*)(ws + 96 * MB);     // 32 MiB (96..128, phiQ dead by dyt1)
  float* T2    = (float*)(ws + 64 * MB);     // 32 MiB (e1 dead after EDFFN)
  float* kvpart = (float*)(ws + 192 * MB);   // 16 MiB [64][C][C]
  float* kvT    = (float*)(ws + 208 * MB);   // 2 MiB [B][C][C]
  float* pose   = (float*)(ws + 210 * MB);   // 4 MiB
  char*  small  = ws + 214 * MB;
  float* ksum  = (float*)(small);
  float* rden  = (float*)(small + 64 * 1024);
  float* pool1 = (float*)(small + 256 * 1024);
  float* pool2 = (float*)(small + 272 * 1024);
  float* gate1 = (float*)(small + 288 * 1024);
  float* gate2 = (float*)(small + 304 * 1024);

  dim3 blk(256);
  const size_t NC = (size_t)NN * CC;

  pos_kern<<<dim3(NN), blk, 0, stream>>>(pose);
  inproj_tile<<<dim3(64, 4, BB), blk, 0, stream>>>(x, in_proj, H);

  // ---- attention ----
  dwconv_psi<<<dim3(4, 64, BB), blk, 0, stream>>>(H, psi_w, psi_b, psiB);
  gemm_mfma<EPI_QK, false, false, float, float, bf16, bf16>
      <<<dim3(256, 2), blk, 0, stream>>>(H, wq_w, wq_b, phiQ, CC, CC, pose, psiB);
  gemm_mfma_T<true><<<dim3(256, 2), blk, 0, stream>>>(H, wk_w, wk_b, phiKT, pose, psiB);
  gemm_mfma_T<false><<<dim3(256, 2), blk, 0, stream>>>(H, wv_w, wv_b, VT, pose, psiB);
  gemm_mfma<EPI_PLAIN, false, true, bf16, bf16, float, float>
      <<<dim3(2, 2, 64), blk, 0, stream>>>(VT, phiKT, nullptr, kvpart, NN, CC, nullptr, nullptr);
  kvred_kern<<<dim3(CC, BB), blk, 0, stream>>>(kvpart, kvT);
  csumT_kern<<<dim3(BB * CC), blk, 0, stream>>>(phiKT, ksum);
  den_kern<<<dim3(NN, BB), blk, 0, stream>>>(phiQ, ksum, rden);
  gemm_mfma<EPI_NUM, true, false, bf16, float, bf16, float>
      <<<dim3(256, 2), blk, 0, stream>>>(phiQ, kvT, nullptr, numb, CC, CC, rden, nullptr);
  gemm_mfma<EPI_BIAS, false, false, bf16, float, float, float>
      <<<dim3(256, 2), blk, 0, stream>>>(numb, wo_w, wo_b, A, CC, CC, nullptr, nullptr);

  // ---- U1 = mona1(dyt(h + a)) ----
  dyt_kern<true><<<dim3(MM), blk, 0, stream>>>(H, A, dyt_g, dyt_b, T1);
  pool_kern<<<dim3(BB, CC), blk, 0, stream>>>(T1, pool1);
  gate_kern<<<dim3(BB), blk, 0, stream>>>(pool1, m1_w, m1_b, gate1);
  scale_kern<<<dim3(MM), blk, 0, stream>>>(T1, gate1, H);   // H = U1

  // ---- EDFFN, 2 passes x 4 batches; e1/e2 bf16 ----
  for (int p = 0; p < 2; ++p) {
    const float* u1p = H + (size_t)(4 * p) * NC;
    float* u2p       = A + (size_t)(4 * p) * NC;
    gemm_mfma<EPI_BIAS, false, false, float, float, bf16, float>
        <<<dim3(128, 8), blk, 0, stream>>>(u1p, we_w, we_b, e1, CC, DH, nullptr, nullptr);
    dwconv1024_bf16<<<dim3(8, 64, 4), blk, 0, stream>>>(e1, dw_w, dw_b, e2);
    gemm_mfma<EPI_RESID, false, false, bf16, float, float, float>
        <<<dim3(128, 2), blk, 0, stream>>>(e2, wp_w, wp_b, u2p, DH, CC, nullptr, u1p);
  }

  // ---- Y = mona2(dyt(U2)) ----
  dyt_kern<false><<<dim3(MM), blk, 0, stream>>>(A, nullptr, dyt_g, dyt_b, T2);
  pool_kern<<<dim3(BB, CC), blk, 0, stream>>>(T2, pool2);
  gate_kern<<<dim3(BB), blk, 0, stream>>>(pool2, m2_w, m2_b, gate2);
  scale_kern<<<dim3(MM), blk, 0, stream>>>(T2, gate2, A);   // A = Y

  // ---- out_proj + SiLU, transposed write ----
  outproj_tile<<<dim3(64, 1, BB), blk, 0, stream>>>(A, wout, out);
}